// Round 9
// baseline (339.462 us; speedup 1.0000x reference)
//
#include <hip/hip_runtime.h>
#include <hip/hip_bf16.h>

// Problem constants (B=4, N=2048, C=768, H=12, D=64)
#define BB 4
#define NN 2048
#define CC 768
#define HH 12
#define DD 64

typedef __bf16 bf16;
typedef __attribute__((ext_vector_type(8))) __bf16 bf16x8;
typedef __attribute__((ext_vector_type(4))) __bf16 bf16x4;
typedef __attribute__((ext_vector_type(4))) float f32x4;

// ---- workspace layout (bf16 elems) ----------------------------------------
#define SZ_X    (BB * NN * CC)              // 6291456
#define SZ_QKVW (3 * CC * CC)               // 1769472
#define SZ_PW   (CC * CC)                   // 589824
#define SZ_QKV  ((size_t)BB * NN * 3 * CC)  // 18874368

#define OFF_X    0
#define OFF_QW   (OFF_X + SZ_X)
#define OFF_PW   (OFF_QW + SZ_QKVW)
#define OFF_QKV  (OFF_PW + SZ_PW)           // end = 27525120 elems = 55.1 MB
// Vt [B*H][D][N] (12.6 MB) lives in d_out lower half; probe scratch in upper.

// Direct-to-LDS 16B DMA; source chunk XOR-swizzled to kill read conflicts.
__device__ __forceinline__ void async16(const bf16* g, bf16* l) {
    __builtin_amdgcn_global_load_lds(
        (const __attribute__((address_space(1))) unsigned int*)g,
        (__attribute__((address_space(3))) unsigned int*)l, 16, 0, 0);
}

// ---------------------------------------------------------------------------
__device__ __forceinline__ void cast8(const float* __restrict__ src,
                                      bf16* __restrict__ dst, int i) {
    f32x4 a = ((const f32x4*)src)[2 * i];
    f32x4 b = ((const f32x4*)src)[2 * i + 1];
    bf16x8 o;
#pragma unroll
    for (int j = 0; j < 4; ++j) { o[j] = (bf16)a[j]; o[j + 4] = (bf16)b[j]; }
    ((bf16x8*)dst)[i] = o;
}

__global__ __launch_bounds__(256) void convert3(
    const float* __restrict__ x, const float* __restrict__ qkvw,
    const float* __restrict__ pw, bf16* __restrict__ ws) {
    const int t = blockIdx.x * 256 + threadIdx.x;
    const int S = gridDim.x * 256;
    for (int i = t; i < SZ_X / 8;    i += S) cast8(x,    ws + OFF_X,  i);
    for (int i = t; i < SZ_QKVW / 8; i += S) cast8(qkvw, ws + OFF_QW, i);
    for (int i = t; i < SZ_PW / 8;   i += S) cast8(pw,   ws + OFF_PW, i);
}

// ---------------------------------------------------------------------------
// QKV GEMM with fused RMSNorm+RoPE epilogue + direct-transposed V store
// (verified rounds 4-5, unchanged).
// ---------------------------------------------------------------------------
__global__ __launch_bounds__(256) void gemm_qkv(
    const bf16* __restrict__ A, const bf16* __restrict__ W,
    bf16* __restrict__ C, bf16* __restrict__ Vt,
    const float* __restrict__ cosb, const float* __restrict__ sinb,
    const float* __restrict__ qw, const float* __restrict__ kw) {
    __shared__ __align__(16) bf16 As[128 * 64];
    __shared__ __align__(16) bf16 Bs[128 * 64];
    const int tid  = threadIdx.x;
    const int wave = tid >> 6;
    const int lane = tid & 63;
    const int quad = lane >> 4;
    const int l16  = lane & 15;
    const int m0 = blockIdx.y * 128;
    const int n0 = blockIdx.x * 128;
    const int wm = (wave >> 1) * 64;
    const int wn = (wave & 1) * 64;
    const int srow = lane >> 3;
    const int swz  = (lane & 7) ^ srow;
    const int K = CC;
    const int Nn = 3 * CC;

    f32x4 acc[4][4];
#pragma unroll
    for (int i = 0; i < 4; ++i)
#pragma unroll
        for (int j = 0; j < 4; ++j) acc[i][j] = (f32x4){0.f, 0.f, 0.f, 0.f};

    for (int k0 = 0; k0 < K; k0 += 64) {
#pragma unroll
        for (int i = 0; i < 4; ++i) {
            int row = i * 32 + wave * 8 + srow;
            async16(A + (size_t)(m0 + row) * CC + k0 + swz * 8,
                    &As[(i * 32 + wave * 8) * 64]);
            async16(W + (size_t)(n0 + row) * K + k0 + swz * 8,
                    &Bs[(i * 32 + wave * 8) * 64]);
        }
        __syncthreads();
#pragma unroll
        for (int kk = 0; kk < 2; ++kk) {
            const int slot = ((kk * 4 + quad) ^ (l16 & 7)) * 8;
            bf16x8 af[4], bf[4];
#pragma unroll
            for (int mt = 0; mt < 4; ++mt)
                af[mt] = *(const bf16x8*)(&As[(wm + mt * 16 + l16) * 64 + slot]);
#pragma unroll
            for (int nt = 0; nt < 4; ++nt)
                bf[nt] = *(const bf16x8*)(&Bs[(wn + nt * 16 + l16) * 64 + slot]);
#pragma unroll
            for (int mt = 0; mt < 4; ++mt)
#pragma unroll
                for (int nt = 0; nt < 4; ++nt)
                    acc[mt][nt] = __builtin_amdgcn_mfma_f32_16x16x32_bf16(
                        af[mt], bf[nt], acc[mt][nt], 0, 0, 0);
        }
        __syncthreads();
    }

    const int colblk = n0 + wn;          // 64-aligned; one head of q/k/v
    const int sector = colblk / CC;      // 0=q, 1=k, 2=v
    if (sector == 2) {
        const int head = (colblk >> 6) - 24;
        const int btok = m0 + wm;
        const int bh   = (btok >> 11) * HH + head;
        const int nloc = btok & (NN - 1);
#pragma unroll
        for (int nt = 0; nt < 4; ++nt) {
            const int d = nt * 16 + l16;
            bf16* dst = Vt + ((size_t)bh * DD + d) * NN + nloc + quad * 4;
#pragma unroll
            for (int mt = 0; mt < 4; ++mt) {
                bf16x4 pk;
#pragma unroll
                for (int r = 0; r < 4; ++r) pk[r] = (bf16)acc[mt][nt][r];
                *(bf16x4*)(dst + mt * 16) = pk;
            }
        }
    } else {
        const float* wp = (sector == 0) ? qw : kw;
        const float qs = (sector == 0) ? 0.18033688f : 1.0f;  // CEXP fold
        float wv[4];
#pragma unroll
        for (int nt = 0; nt < 4; ++nt) wv[nt] = wp[nt * 16 + l16];
#pragma unroll
        for (int mt = 0; mt < 4; ++mt)
#pragma unroll
            for (int r = 0; r < 4; ++r) {
                const int row = m0 + wm + mt * 16 + quad * 4 + r;
                const int n   = row & (NN - 1);
                float v[4];
#pragma unroll
                for (int nt = 0; nt < 4; ++nt) v[nt] = acc[mt][nt][r];
                float ss = v[0] * v[0] + v[1] * v[1] + v[2] * v[2] + v[3] * v[3];
                ss += __shfl_xor(ss, 1, 64);
                ss += __shfl_xor(ss, 2, 64);
                ss += __shfl_xor(ss, 4, 64);
                ss += __shfl_xor(ss, 8, 64);
                const float rn = rsqrtf(ss * (1.0f / 64.0f) + 1e-6f);
#pragma unroll
                for (int nt = 0; nt < 4; ++nt) v[nt] *= rn * wv[nt];
                const float c0 = cosb[n * 32 + l16];
                const float c1 = cosb[n * 32 + 16 + l16];
                const float s0 = sinb[n * 32 + l16];
                const float s1 = sinb[n * 32 + 16 + l16];
                float y[4];
                y[0] = v[0] * c0 - v[2] * s0;
                y[1] = v[1] * c1 - v[3] * s1;
                y[2] = v[2] * c0 + v[0] * s0;
                y[3] = v[3] * c1 + v[1] * s1;
#pragma unroll
                for (int nt = 0; nt < 4; ++nt) {
                    int col = colblk + nt * 16 + l16;
                    C[(size_t)row * Nn + col] = (bf16)(y[nt] * qs);
                }
            }
    }
}

// ---------------------------------------------------------------------------
// Output projection GEMM, 128x64 tiles (verified round 5, unchanged).
// ---------------------------------------------------------------------------
__global__ __launch_bounds__(256) void gemm_proj(
    const bf16* __restrict__ A, const bf16* __restrict__ W,
    const float* __restrict__ bias, float* __restrict__ C) {
    __shared__ __align__(16) bf16 As[128 * 64];
    __shared__ __align__(16) bf16 Bs[64 * 64];
    const int tid  = threadIdx.x;
    const int wave = tid >> 6;
    const int lane = tid & 63;
    const int quad = lane >> 4;
    const int l16  = lane & 15;
    const int m0 = blockIdx.y * 128;
    const int n0 = blockIdx.x * 64;
    const int wm = (wave >> 1) * 64;
    const int wn = (wave & 1) * 32;
    const int srow = lane >> 3;
    const int swz  = (lane & 7) ^ srow;
    const int lda = 3 * CC;
    const int K = CC;

    f32x4 acc[4][2];
#pragma unroll
    for (int i = 0; i < 4; ++i)
#pragma unroll
        for (int j = 0; j < 2; ++j) acc[i][j] = (f32x4){0.f, 0.f, 0.f, 0.f};

    for (int k0 = 0; k0 < K; k0 += 64) {
#pragma unroll
        for (int i = 0; i < 4; ++i) {
            int row = i * 32 + wave * 8 + srow;
            async16(A + (size_t)(m0 + row) * lda + k0 + swz * 8,
                    &As[(i * 32 + wave * 8) * 64]);
        }
#pragma unroll
        for (int i = 0; i < 2; ++i) {
            int row = i * 32 + wave * 8 + srow;
            async16(W + (size_t)(n0 + row) * K + k0 + swz * 8,
                    &Bs[(i * 32 + wave * 8) * 64]);
        }
        __syncthreads();
#pragma unroll
        for (int kk = 0; kk < 2; ++kk) {
            const int slot = ((kk * 4 + quad) ^ (l16 & 7)) * 8;
            bf16x8 af[4], bf[2];
#pragma unroll
            for (int mt = 0; mt < 4; ++mt)
                af[mt] = *(const bf16x8*)(&As[(wm + mt * 16 + l16) * 64 + slot]);
#pragma unroll
            for (int nt = 0; nt < 2; ++nt)
                bf[nt] = *(const bf16x8*)(&Bs[(wn + nt * 16 + l16) * 64 + slot]);
#pragma unroll
            for (int mt = 0; mt < 4; ++mt)
#pragma unroll
                for (int nt = 0; nt < 2; ++nt)
                    acc[mt][nt] = __builtin_amdgcn_mfma_f32_16x16x32_bf16(
                        af[mt], bf[nt], acc[mt][nt], 0, 0, 0);
        }
        __syncthreads();
    }
#pragma unroll
    for (int mt = 0; mt < 4; ++mt)
#pragma unroll
        for (int nt = 0; nt < 2; ++nt)
#pragma unroll
            for (int r = 0; r < 4; ++r) {
                int row = m0 + wm + mt * 16 + quad * 4 + r;
                int col = n0 + wn + nt * 16 + l16;
                C[(size_t)row * CC + col] = acc[mt][nt][r] + bias[col];
            }
}

// ---------------------------------------------------------------------------
// Flash attention — round-6 version restored (best measured: 74.2us, Occ 50%).
// 8 waves x 16 q-rows, 512 threads, single-buffered, 2 barriers/tile.
// ---------------------------------------------------------------------------
__global__ __launch_bounds__(512) void flash_attn(
    const bf16* __restrict__ qkv, const bf16* __restrict__ Vt,
    bf16* __restrict__ Oqkv) {
    __shared__ __align__(16) bf16 Ks[64 * 64];       // [key][d] swizzled
    __shared__ __align__(16) bf16 Vs[64 * 64];       // [d][key] swizzled
    __shared__ __align__(16) bf16 Ps[8][16 * 72];    // per-wave [q][key], padded
    const int tid  = threadIdx.x;
    const int wave = tid >> 6;
    const int lane = tid & 63;
    const int quad = lane >> 4;
    const int l16  = lane & 15;
    const int r7   = l16 & 7;
    const int bh = blockIdx.x;
    const int qt = blockIdx.y;
    const int b = bh / HH, h = bh % HH;
    const size_t rs = 3 * CC;
    const bf16* Qb  = qkv + (size_t)b * NN * rs + h * DD;
    const bf16* Kb  = Qb + CC;
    const bf16* Vtb = Vt + (size_t)bh * DD * NN;

    bf16x8 qf[2];
    {
        const int qrow = qt * 128 + wave * 16 + l16;
#pragma unroll
        for (int hf = 0; hf < 2; ++hf)
            qf[hf] = *(const bf16x8*)(Qb + (size_t)qrow * rs + hf * 32 + quad * 8);
    }

    f32x4 accO[4];
#pragma unroll
    for (int i = 0; i < 4; ++i) accO[i] = (f32x4){0.f, 0.f, 0.f, 0.f};
    float lsum = 0.f;

    const int srow = lane >> 3;
    const int swz  = (lane & 7) ^ srow;
    const int strow = wave * 8 + srow;

    for (int kt = 0; kt < NN / 64; ++kt) {
        async16(Kb + (size_t)(kt * 64 + strow) * rs + swz * 8,
                &Ks[(wave * 8) * 64]);
        async16(Vtb + (size_t)strow * NN + kt * 64 + swz * 8,
                &Vs[(wave * 8) * 64]);
        __syncthreads();

        f32x4 s[4];
#pragma unroll
        for (int nt = 0; nt < 4; ++nt) {
            const int row = nt * 16 + l16;
            bf16x8 kf0 = *(const bf16x8*)(&Ks[row * 64 + (quad ^ r7) * 8]);
            bf16x8 kf1 = *(const bf16x8*)(&Ks[row * 64 + ((quad + 4) ^ r7) * 8]);
            f32x4 z = (f32x4){0.f, 0.f, 0.f, 0.f};
            z = __builtin_amdgcn_mfma_f32_16x16x32_bf16(kf0, qf[0], z, 0, 0, 0);
            s[nt] = __builtin_amdgcn_mfma_f32_16x16x32_bf16(kf1, qf[1], z, 0, 0, 0);
        }

#pragma unroll
        for (int nt = 0; nt < 4; ++nt) {
            bf16x4 pk;
#pragma unroll
            for (int r = 0; r < 4; ++r) {
                float pv = __builtin_amdgcn_exp2f(s[nt][r]);
                lsum += pv;
                pk[r] = (bf16)pv;
            }
            *(bf16x4*)(&Ps[wave][l16 * 72 + nt * 16 + quad * 4]) = pk;
        }
        __asm__ volatile("s_waitcnt lgkmcnt(0)" ::: "memory");

        bf16x8 pf0 = *(const bf16x8*)(&Ps[wave][l16 * 72 + quad * 8]);
        bf16x8 pf1 = *(const bf16x8*)(&Ps[wave][l16 * 72 + 32 + quad * 8]);
#pragma unroll
        for (int nt = 0; nt < 4; ++nt) {
            const int rowd = nt * 16 + l16;
            bf16x8 vf0 = *(const bf16x8*)(&Vs[rowd * 64 + (quad ^ r7) * 8]);
            bf16x8 vf1 = *(const bf16x8*)(&Vs[rowd * 64 + ((quad + 4) ^ r7) * 8]);
            accO[nt] = __builtin_amdgcn_mfma_f32_16x16x32_bf16(pf0, vf0, accO[nt], 0, 0, 0);
            accO[nt] = __builtin_amdgcn_mfma_f32_16x16x32_bf16(pf1, vf1, accO[nt], 0, 0, 0);
        }
        __syncthreads();
    }

    lsum += __shfl_xor(lsum, 16, 64);
    lsum += __shfl_xor(lsum, 32, 64);

#pragma unroll
    for (int r = 0; r < 4; ++r) {
        float inv = 1.0f / __shfl(lsum, quad * 4 + r, 64);
        int n = qt * 128 + wave * 16 + quad * 4 + r;
#pragma unroll
        for (int nt = 0; nt < 4; ++nt) {
            int col = h * DD + nt * 16 + l16;
            Oqkv[(size_t)(b * NN + n) * rs + 2 * CC + col] = (bf16)(accO[nt][r] * inv);
        }
    }
}

// ---------------------------------------------------------------------------
// ABLATION PROBES (round 9, instrumentation): template variants of the
// round-6 flash body.  Write only a per-thread token to dead scratch (upper
// half of d_out); launched after the real flash, before gemm_proj, so
// correctness is unaffected.  Keep-alive via token accumulation (rule #17 —
// no asm needed, values feed the store).
//   NOPV  = full minus {Ps read, V reads, PV MFMAs}   (exp alive via lsum)
//   NOSM  = full minus {exp, lsum, pack, Ps RT}; s alive via token; pf := qf
//   STAGE = DMA + barriers only (DMA intrinsic side-effecting, not DCE-able)
// ---------------------------------------------------------------------------
#define PM_NOPV  1
#define PM_NOSM  2
#define PM_STAGE 3

template <int MODE>
__global__ __launch_bounds__(512) void flash_probe(
    const bf16* __restrict__ qkv, const bf16* __restrict__ Vt,
    float* __restrict__ Oscr) {
    __shared__ __align__(16) bf16 Ks[64 * 64];
    __shared__ __align__(16) bf16 Vs[64 * 64];
    __shared__ __align__(16) bf16 Ps[8][16 * 72];
    const int tid  = threadIdx.x;
    const int wave = tid >> 6;
    const int lane = tid & 63;
    const int quad = lane >> 4;
    const int l16  = lane & 15;
    const int r7   = l16 & 7;
    const int bh = blockIdx.x;
    const int qt = blockIdx.y;
    const int b = bh / HH, h = bh % HH;
    const size_t rs = 3 * CC;
    const bf16* Qb  = qkv + (size_t)b * NN * rs + h * DD;
    const bf16* Kb  = Qb + CC;
    const bf16* Vtb = Vt + (size_t)bh * DD * NN;

    bf16x8 qf[2];
    {
        const int qrow = qt * 128 + wave * 16 + l16;
#pragma unroll
        for (int hf = 0; hf < 2; ++hf)
            qf[hf] = *(const bf16x8*)(Qb + (size_t)qrow * rs + hf * 32 + quad * 8);
    }

    f32x4 accO[4];
#pragma unroll
    for (int i = 0; i < 4; ++i) accO[i] = (f32x4){0.f, 0.f, 0.f, 0.f};
    float lsum = 0.f;
    float tok  = 0.f;

    const int srow = lane >> 3;
    const int swz  = (lane & 7) ^ srow;
    const int strow = wave * 8 + srow;

    for (int kt = 0; kt < NN / 64; ++kt) {
        async16(Kb + (size_t)(kt * 64 + strow) * rs + swz * 8,
                &Ks[(wave * 8) * 64]);
        async16(Vtb + (size_t)strow * NN + kt * 64 + swz * 8,
                &Vs[(wave * 8) * 64]);
        __syncthreads();

        if constexpr (MODE != PM_STAGE) {
            f32x4 s[4];
#pragma unroll
            for (int nt = 0; nt < 4; ++nt) {
                const int row = nt * 16 + l16;
                bf16x8 kf0 = *(const bf16x8*)(&Ks[row * 64 + (quad ^ r7) * 8]);
                bf16x8 kf1 = *(const bf16x8*)(&Ks[row * 64 + ((quad + 4) ^ r7) * 8]);
                f32x4 z = (f32x4){0.f, 0.f, 0.f, 0.f};
                z = __builtin_amdgcn_mfma_f32_16x16x32_bf16(kf0, qf[0], z, 0, 0, 0);
                s[nt] = __builtin_amdgcn_mfma_f32_16x16x32_bf16(kf1, qf[1], z, 0, 0, 0);
            }

            if constexpr (MODE == PM_NOSM) {
                // keep QK results alive; skip softmax entirely
#pragma unroll
                for (int nt = 0; nt < 4; ++nt)
#pragma unroll
                    for (int r = 0; r < 4; ++r) tok += s[nt][r];
                bf16x8 pf0 = qf[0], pf1 = qf[1];
#pragma unroll
                for (int nt = 0; nt < 4; ++nt) {
                    const int rowd = nt * 16 + l16;
                    bf16x8 vf0 = *(const bf16x8*)(&Vs[rowd * 64 + (quad ^ r7) * 8]);
                    bf16x8 vf1 = *(const bf16x8*)(&Vs[rowd * 64 + ((quad + 4) ^ r7) * 8]);
                    accO[nt] = __builtin_amdgcn_mfma_f32_16x16x32_bf16(pf0, vf0, accO[nt], 0, 0, 0);
                    accO[nt] = __builtin_amdgcn_mfma_f32_16x16x32_bf16(pf1, vf1, accO[nt], 0, 0, 0);
                }
            } else {
                // softmax phase (FULL and NOPV)
#pragma unroll
                for (int nt = 0; nt < 4; ++nt) {
                    bf16x4 pk;
#pragma unroll
                    for (int r = 0; r < 4; ++r) {
                        float pv = __builtin_amdgcn_exp2f(s[nt][r]);
                        lsum += pv;
                        pk[r] = (bf16)pv;
                    }
                    *(bf16x4*)(&Ps[wave][l16 * 72 + nt * 16 + quad * 4]) = pk;
                }
                __asm__ volatile("s_waitcnt lgkmcnt(0)" ::: "memory");
                if constexpr (MODE != PM_NOPV) {
                    bf16x8 pf0 = *(const bf16x8*)(&Ps[wave][l16 * 72 + quad * 8]);
                    bf16x8 pf1 = *(const bf16x8*)(&Ps[wave][l16 * 72 + 32 + quad * 8]);
#pragma unroll
                    for (int nt = 0; nt < 4; ++nt) {
                        const int rowd = nt * 16 + l16;
                        bf16x8 vf0 = *(const bf16x8*)(&Vs[rowd * 64 + (quad ^ r7) * 8]);
                        bf16x8 vf1 = *(const bf16x8*)(&Vs[rowd * 64 + ((quad + 4) ^ r7) * 8]);
                        accO[nt] = __builtin_amdgcn_mfma_f32_16x16x32_bf16(pf0, vf0, accO[nt], 0, 0, 0);
                        accO[nt] = __builtin_amdgcn_mfma_f32_16x16x32_bf16(pf1, vf1, accO[nt], 0, 0, 0);
                    }
                }
            }
        }
        __syncthreads();
    }

    // keep everything live with one compact store per thread
    tok += lsum;
#pragma unroll
    for (int nt = 0; nt < 4; ++nt)
#pragma unroll
        for (int r = 0; r < 4; ++r) tok += accO[nt][r];
    const int gid = (bh * gridDim.y + qt) * 512 + tid;
    Oscr[gid] = tok;
}

// ---------------------------------------------------------------------------
extern "C" void kernel_launch(void* const* d_in, const int* in_sizes, int n_in,
                              void* d_out, int out_size, void* d_ws, size_t ws_size,
                              hipStream_t stream) {
    const float* x     = (const float*)d_in[0];
    const float* cosb  = (const float*)d_in[1];
    const float* sinb  = (const float*)d_in[2];
    const float* qkv_w = (const float*)d_in[3];
    const float* qnw   = (const float*)d_in[4];
    const float* knw   = (const float*)d_in[5];
    const float* pw    = (const float*)d_in[6];
    const float* pb    = (const float*)d_in[7];
    float* out = (float*)d_out;

    bf16* ws  = (bf16*)d_ws;
    bf16* xb  = ws + OFF_X;
    bf16* qwb = ws + OFF_QW;
    bf16* pwb = ws + OFF_PW;
    bf16* qkv = ws + OFF_QKV;
    bf16* vt  = (bf16*)d_out;          // lower 12.6 MB of out (dead until proj)
    float* oscr = out + 3145728;       // upper 12.6 MB of out: probe scratch

    const int M = BB * NN;  // 8192

    // 0) cast MFMA operands to bf16
    convert3<<<1024, 256, 0, stream>>>(x, qkv_w, pw, ws);

    // 1) QKV projection + fused RMSNorm/RoPE/CEXP; v written transposed to Vt
    dim3 g1(3 * CC / 128, M / 128);
    gemm_qkv<<<g1, 256, 0, stream>>>(xb, qwb, qkv, vt, cosb, sinb, qnw, knw);

    // 2) Flash attention (round-6 config) -> v-slice of qkv
    dim3 g4(BB * HH, NN / 128);
    flash_attn<<<g4, 512, 0, stream>>>(qkv, vt, qkv);

    // 2b) ABLATION PROBES (instrumentation round) — write to dead scratch
    flash_probe<PM_NOPV ><<<g4, 512, 0, stream>>>(qkv, vt, oscr);
    flash_probe<PM_NOSM ><<<g4, 512, 0, stream>>>(qkv, vt, oscr);
    flash_probe<PM_STAGE><<<g4, 512, 0, stream>>>(qkv, vt, oscr);

    // 3) Output projection (+fp32 bias) -> d_out (overwrites all scratch)
    dim3 g5(CC / 64, M / 128);
    gemm_proj<<<g5, 256, 0, stream>>>(qkv + 2 * CC, pwb, pb, out);
}

// Round 10
// 231.423 us; speedup vs baseline: 1.4668x; 1.4668x over previous
//
#include <hip/hip_runtime.h>
#include <hip/hip_bf16.h>

// Problem constants (B=4, N=2048, C=768, H=12, D=64)
#define BB 4
#define NN 2048
#define CC 768
#define HH 12
#define DD 64

typedef __bf16 bf16;
typedef __attribute__((ext_vector_type(8))) __bf16 bf16x8;
typedef __attribute__((ext_vector_type(4))) __bf16 bf16x4;
typedef __attribute__((ext_vector_type(4))) float f32x4;

// ---- workspace layout (bf16 elems) ----------------------------------------
#define SZ_X    (BB * NN * CC)              // 6291456
#define SZ_QKVW (3 * CC * CC)               // 1769472
#define SZ_PW   (CC * CC)                   // 589824
#define SZ_QKV  ((size_t)BB * NN * 3 * CC)  // 18874368

#define OFF_X    0
#define OFF_QW   (OFF_X + SZ_X)
#define OFF_PW   (OFF_QW + SZ_QKVW)
#define OFF_QKV  (OFF_PW + SZ_PW)           // end = 27525120 elems = 55.1 MB
// Vt [B*H][D][N] (12.6 MB) lives in d_out (25.2 MB f32 scratch until proj).

// Direct-to-LDS 16B DMA; source chunk XOR-swizzled to kill read conflicts.
__device__ __forceinline__ void async16(const bf16* g, bf16* l) {
    __builtin_amdgcn_global_load_lds(
        (const __attribute__((address_space(1))) unsigned int*)g,
        (__attribute__((address_space(3))) unsigned int*)l, 16, 0, 0);
}

// ---------------------------------------------------------------------------
__device__ __forceinline__ void cast8(const float* __restrict__ src,
                                      bf16* __restrict__ dst, int i) {
    f32x4 a = ((const f32x4*)src)[2 * i];
    f32x4 b = ((const f32x4*)src)[2 * i + 1];
    bf16x8 o;
#pragma unroll
    for (int j = 0; j < 4; ++j) { o[j] = (bf16)a[j]; o[j + 4] = (bf16)b[j]; }
    ((bf16x8*)dst)[i] = o;
}

__global__ __launch_bounds__(256) void convert3(
    const float* __restrict__ x, const float* __restrict__ qkvw,
    const float* __restrict__ pw, bf16* __restrict__ ws) {
    const int t = blockIdx.x * 256 + threadIdx.x;
    const int S = gridDim.x * 256;
    for (int i = t; i < SZ_X / 8;    i += S) cast8(x,    ws + OFF_X,  i);
    for (int i = t; i < SZ_QKVW / 8; i += S) cast8(qkvw, ws + OFF_QW, i);
    for (int i = t; i < SZ_PW / 8;   i += S) cast8(pw,   ws + OFF_PW, i);
}

// ---------------------------------------------------------------------------
// QKV GEMM with fused RMSNorm+RoPE epilogue + direct-transposed V store
// (verified rounds 4-5, unchanged).
// ---------------------------------------------------------------------------
__global__ __launch_bounds__(256) void gemm_qkv(
    const bf16* __restrict__ A, const bf16* __restrict__ W,
    bf16* __restrict__ C, bf16* __restrict__ Vt,
    const float* __restrict__ cosb, const float* __restrict__ sinb,
    const float* __restrict__ qw, const float* __restrict__ kw) {
    __shared__ __align__(16) bf16 As[128 * 64];
    __shared__ __align__(16) bf16 Bs[128 * 64];
    const int tid  = threadIdx.x;
    const int wave = tid >> 6;
    const int lane = tid & 63;
    const int quad = lane >> 4;
    const int l16  = lane & 15;
    const int m0 = blockIdx.y * 128;
    const int n0 = blockIdx.x * 128;
    const int wm = (wave >> 1) * 64;
    const int wn = (wave & 1) * 64;
    const int srow = lane >> 3;
    const int swz  = (lane & 7) ^ srow;
    const int K = CC;
    const int Nn = 3 * CC;

    f32x4 acc[4][4];
#pragma unroll
    for (int i = 0; i < 4; ++i)
#pragma unroll
        for (int j = 0; j < 4; ++j) acc[i][j] = (f32x4){0.f, 0.f, 0.f, 0.f};

    for (int k0 = 0; k0 < K; k0 += 64) {
#pragma unroll
        for (int i = 0; i < 4; ++i) {
            int row = i * 32 + wave * 8 + srow;
            async16(A + (size_t)(m0 + row) * CC + k0 + swz * 8,
                    &As[(i * 32 + wave * 8) * 64]);
            async16(W + (size_t)(n0 + row) * K + k0 + swz * 8,
                    &Bs[(i * 32 + wave * 8) * 64]);
        }
        __syncthreads();
#pragma unroll
        for (int kk = 0; kk < 2; ++kk) {
            const int slot = ((kk * 4 + quad) ^ (l16 & 7)) * 8;
            bf16x8 af[4], bf[4];
#pragma unroll
            for (int mt = 0; mt < 4; ++mt)
                af[mt] = *(const bf16x8*)(&As[(wm + mt * 16 + l16) * 64 + slot]);
#pragma unroll
            for (int nt = 0; nt < 4; ++nt)
                bf[nt] = *(const bf16x8*)(&Bs[(wn + nt * 16 + l16) * 64 + slot]);
#pragma unroll
            for (int mt = 0; mt < 4; ++mt)
#pragma unroll
                for (int nt = 0; nt < 4; ++nt)
                    acc[mt][nt] = __builtin_amdgcn_mfma_f32_16x16x32_bf16(
                        af[mt], bf[nt], acc[mt][nt], 0, 0, 0);
        }
        __syncthreads();
    }

    const int colblk = n0 + wn;          // 64-aligned; one head of q/k/v
    const int sector = colblk / CC;      // 0=q, 1=k, 2=v
    if (sector == 2) {
        const int head = (colblk >> 6) - 24;
        const int btok = m0 + wm;
        const int bh   = (btok >> 11) * HH + head;
        const int nloc = btok & (NN - 1);
#pragma unroll
        for (int nt = 0; nt < 4; ++nt) {
            const int d = nt * 16 + l16;
            bf16* dst = Vt + ((size_t)bh * DD + d) * NN + nloc + quad * 4;
#pragma unroll
            for (int mt = 0; mt < 4; ++mt) {
                bf16x4 pk;
#pragma unroll
                for (int r = 0; r < 4; ++r) pk[r] = (bf16)acc[mt][nt][r];
                *(bf16x4*)(dst + mt * 16) = pk;
            }
        }
    } else {
        const float* wp = (sector == 0) ? qw : kw;
        const float qs = (sector == 0) ? 0.18033688f : 1.0f;  // CEXP fold
        float wv[4];
#pragma unroll
        for (int nt = 0; nt < 4; ++nt) wv[nt] = wp[nt * 16 + l16];
#pragma unroll
        for (int mt = 0; mt < 4; ++mt)
#pragma unroll
            for (int r = 0; r < 4; ++r) {
                const int row = m0 + wm + mt * 16 + quad * 4 + r;
                const int n   = row & (NN - 1);
                float v[4];
#pragma unroll
                for (int nt = 0; nt < 4; ++nt) v[nt] = acc[mt][nt][r];
                float ss = v[0] * v[0] + v[1] * v[1] + v[2] * v[2] + v[3] * v[3];
                ss += __shfl_xor(ss, 1, 64);
                ss += __shfl_xor(ss, 2, 64);
                ss += __shfl_xor(ss, 4, 64);
                ss += __shfl_xor(ss, 8, 64);
                const float rn = rsqrtf(ss * (1.0f / 64.0f) + 1e-6f);
#pragma unroll
                for (int nt = 0; nt < 4; ++nt) v[nt] *= rn * wv[nt];
                const float c0 = cosb[n * 32 + l16];
                const float c1 = cosb[n * 32 + 16 + l16];
                const float s0 = sinb[n * 32 + l16];
                const float s1 = sinb[n * 32 + 16 + l16];
                float y[4];
                y[0] = v[0] * c0 - v[2] * s0;
                y[1] = v[1] * c1 - v[3] * s1;
                y[2] = v[2] * c0 + v[0] * s0;
                y[3] = v[3] * c1 + v[1] * s1;
#pragma unroll
                for (int nt = 0; nt < 4; ++nt) {
                    int col = colblk + nt * 16 + l16;
                    C[(size_t)row * Nn + col] = (bf16)(y[nt] * qs);
                }
            }
    }
}

// ---------------------------------------------------------------------------
// Output projection GEMM, 128x64 tiles (verified round 5, unchanged).
// ---------------------------------------------------------------------------
__global__ __launch_bounds__(256) void gemm_proj(
    const bf16* __restrict__ A, const bf16* __restrict__ W,
    const float* __restrict__ bias, float* __restrict__ C) {
    __shared__ __align__(16) bf16 As[128 * 64];
    __shared__ __align__(16) bf16 Bs[64 * 64];
    const int tid  = threadIdx.x;
    const int wave = tid >> 6;
    const int lane = tid & 63;
    const int quad = lane >> 4;
    const int l16  = lane & 15;
    const int m0 = blockIdx.y * 128;
    const int n0 = blockIdx.x * 64;
    const int wm = (wave >> 1) * 64;
    const int wn = (wave & 1) * 32;
    const int srow = lane >> 3;
    const int swz  = (lane & 7) ^ srow;
    const int lda = 3 * CC;
    const int K = CC;

    f32x4 acc[4][2];
#pragma unroll
    for (int i = 0; i < 4; ++i)
#pragma unroll
        for (int j = 0; j < 2; ++j) acc[i][j] = (f32x4){0.f, 0.f, 0.f, 0.f};

    for (int k0 = 0; k0 < K; k0 += 64) {
#pragma unroll
        for (int i = 0; i < 4; ++i) {
            int row = i * 32 + wave * 8 + srow;
            async16(A + (size_t)(m0 + row) * lda + k0 + swz * 8,
                    &As[(i * 32 + wave * 8) * 64]);
        }
#pragma unroll
        for (int i = 0; i < 2; ++i) {
            int row = i * 32 + wave * 8 + srow;
            async16(W + (size_t)(n0 + row) * K + k0 + swz * 8,
                    &Bs[(i * 32 + wave * 8) * 64]);
        }
        __syncthreads();
#pragma unroll
        for (int kk = 0; kk < 2; ++kk) {
            const int slot = ((kk * 4 + quad) ^ (l16 & 7)) * 8;
            bf16x8 af[4], bf[2];
#pragma unroll
            for (int mt = 0; mt < 4; ++mt)
                af[mt] = *(const bf16x8*)(&As[(wm + mt * 16 + l16) * 64 + slot]);
#pragma unroll
            for (int nt = 0; nt < 2; ++nt)
                bf[nt] = *(const bf16x8*)(&Bs[(wn + nt * 16 + l16) * 64 + slot]);
#pragma unroll
            for (int mt = 0; mt < 4; ++mt)
#pragma unroll
                for (int nt = 0; nt < 2; ++nt)
                    acc[mt][nt] = __builtin_amdgcn_mfma_f32_16x16x32_bf16(
                        af[mt], bf[nt], acc[mt][nt], 0, 0, 0);
        }
        __syncthreads();
    }
#pragma unroll
    for (int mt = 0; mt < 4; ++mt)
#pragma unroll
        for (int nt = 0; nt < 2; ++nt)
#pragma unroll
            for (int r = 0; r < 4; ++r) {
                int row = m0 + wm + mt * 16 + quad * 4 + r;
                int col = n0 + wn + nt * 16 + l16;
                C[(size_t)row * CC + col] = acc[mt][nt][r] + bias[col];
            }
}

// ---------------------------------------------------------------------------
// Flash attention, round-10: Ps LDS round-trip ELIMINATED via contraction
// relabeling.  MFMA computes sum_k A[m][k]B[k][n] for ANY joint k->key
// bijection.  Pick key(quad,j) = (j>>2)*16 + quad*4 + (j&3): then the PV
// A-fragment (k = quad*8+j, the verified frag mapping) is exactly the 8
// p-values this lane already holds from swapped QK^T (p[nt][r] sits at
// key = nt*16+quad*4+r, q = l16).  pf = pure in-register packing; the
// matching V B-fragment reads 4x ds_read_b64 per nt at the relabeled keys
// (same bytes as the old 2x b128; swizzle spreads banks 8-way, 2-way
// aliasing = free).  Removes per wave per tile: 4 ds_write + 2 ds_read_b128
// + lgkmcnt(0) drain (-20% on the saturated DS pipe, per the r9 ablation
// model).  Ps deleted: LDS 34.8K -> 16.4K.  Shape = round-6 (8 waves x 16q,
// 512 thr, best measured 74.2us).
// ---------------------------------------------------------------------------
__global__ __launch_bounds__(512) void flash_attn(
    const bf16* __restrict__ qkv, const bf16* __restrict__ Vt,
    bf16* __restrict__ Oqkv) {
    __shared__ __align__(16) bf16 Ks[64 * 64];       // [key][d] swizzled
    __shared__ __align__(16) bf16 Vs[64 * 64];       // [d][key] swizzled
    const int tid  = threadIdx.x;
    const int wave = tid >> 6;
    const int lane = tid & 63;
    const int quad = lane >> 4;
    const int l16  = lane & 15;
    const int r7   = l16 & 7;
    const int bh = blockIdx.x;
    const int qt = blockIdx.y;
    const int b = bh / HH, h = bh % HH;
    const size_t rs = 3 * CC;
    const bf16* Qb  = qkv + (size_t)b * NN * rs + h * DD;
    const bf16* Kb  = Qb + CC;
    const bf16* Vtb = Vt + (size_t)bh * DD * NN;

    bf16x8 qf[2];
    {
        const int qrow = qt * 128 + wave * 16 + l16;
#pragma unroll
        for (int hf = 0; hf < 2; ++hf)
            qf[hf] = *(const bf16x8*)(Qb + (size_t)qrow * rs + hf * 32 + quad * 8);
    }

    f32x4 accO[4];
#pragma unroll
    for (int i = 0; i < 4; ++i) accO[i] = (f32x4){0.f, 0.f, 0.f, 0.f};
    float lsum = 0.f;

    const int srow = lane >> 3;
    const int swz  = (lane & 7) ^ srow;
    const int strow = wave * 8 + srow;
    const int sub   = (quad & 1) * 4;        // 4-elem offset within an 8-chunk
    const int ghalf = quad >> 1;             // chunk base for this quad

    for (int kt = 0; kt < NN / 64; ++kt) {
        async16(Kb + (size_t)(kt * 64 + strow) * rs + swz * 8,
                &Ks[(wave * 8) * 64]);
        async16(Vtb + (size_t)strow * NN + kt * 64 + swz * 8,
                &Vs[(wave * 8) * 64]);
        __syncthreads();

        // S^T = (Q K^T)^T via swapped operands; scores already exp2-domain
        f32x4 s[4];
#pragma unroll
        for (int nt = 0; nt < 4; ++nt) {
            const int row = nt * 16 + l16;
            bf16x8 kf0 = *(const bf16x8*)(&Ks[row * 64 + (quad ^ r7) * 8]);
            bf16x8 kf1 = *(const bf16x8*)(&Ks[row * 64 + ((quad + 4) ^ r7) * 8]);
            f32x4 z = (f32x4){0.f, 0.f, 0.f, 0.f};
            z = __builtin_amdgcn_mfma_f32_16x16x32_bf16(kf0, qf[0], z, 0, 0, 0);
            s[nt] = __builtin_amdgcn_mfma_f32_16x16x32_bf16(kf1, qf[1], z, 0, 0, 0);
        }

        // p = exp2(s); pack IN-LANE into PV A-fragments (no LDS round-trip):
        // pf_a[j] = p[j>>2][j&3]  (keys (j>>2)*16 + quad*4 + (j&3))
        // pf_b[j] = p[2+(j>>2)][j&3]  (+32)
        bf16x8 pfa, pfb;
#pragma unroll
        for (int nt = 0; nt < 4; ++nt)
#pragma unroll
            for (int r = 0; r < 4; ++r) {
                float pv = __builtin_amdgcn_exp2f(s[nt][r]);
                lsum += pv;
                if (nt < 2) pfa[nt * 4 + r] = (bf16)pv;
                else        pfb[(nt - 2) * 4 + r] = (bf16)pv;
            }

        // PV with relabeled keys: B-frag j -> V[key(quad,j)][d=nt*16+l16].
        // 4-elem groups live in swizzled chunks {ghalf, 2+ghalf} (pfa) and
        // {4+ghalf, 6+ghalf} (pfb) at sub-offset (quad&1)*4.
#pragma unroll
        for (int nt = 0; nt < 4; ++nt) {
            const int rowb = (nt * 16 + l16) * 64;
            bf16x4 va0 = *(const bf16x4*)(&Vs[rowb + ((ghalf     ^ r7) * 8) + sub]);
            bf16x4 va1 = *(const bf16x4*)(&Vs[rowb + (((2 + ghalf) ^ r7) * 8) + sub]);
            bf16x4 vb0 = *(const bf16x4*)(&Vs[rowb + (((4 + ghalf) ^ r7) * 8) + sub]);
            bf16x4 vb1 = *(const bf16x4*)(&Vs[rowb + (((6 + ghalf) ^ r7) * 8) + sub]);
            bf16x8 vfa, vfb;
#pragma unroll
            for (int j = 0; j < 4; ++j) {
                vfa[j] = va0[j]; vfa[4 + j] = va1[j];
                vfb[j] = vb0[j]; vfb[4 + j] = vb1[j];
            }
            accO[nt] = __builtin_amdgcn_mfma_f32_16x16x32_bf16(pfa, vfa, accO[nt], 0, 0, 0);
            accO[nt] = __builtin_amdgcn_mfma_f32_16x16x32_bf16(pfb, vfb, accO[nt], 0, 0, 0);
        }
        __syncthreads();
    }

    // lsum: lane holds partial for q=l16 over its 16 keys; reduce over quads
    lsum += __shfl_xor(lsum, 16, 64);
    lsum += __shfl_xor(lsum, 32, 64);

    // epilogue: accO row q = quad*4+r; fetch 1/lsum from lane quad*4+r
#pragma unroll
    for (int r = 0; r < 4; ++r) {
        float inv = 1.0f / __shfl(lsum, quad * 4 + r, 64);
        int n = qt * 128 + wave * 16 + quad * 4 + r;
#pragma unroll
        for (int nt = 0; nt < 4; ++nt) {
            int col = h * DD + nt * 16 + l16;
            Oqkv[(size_t)(b * NN + n) * rs + 2 * CC + col] = (bf16)(accO[nt][r] * inv);
        }
    }
}

// ---------------------------------------------------------------------------
extern "C" void kernel_launch(void* const* d_in, const int* in_sizes, int n_in,
                              void* d_out, int out_size, void* d_ws, size_t ws_size,
                              hipStream_t stream) {
    const float* x     = (const float*)d_in[0];
    const float* cosb  = (const float*)d_in[1];
    const float* sinb  = (const float*)d_in[2];
    const float* qkv_w = (const float*)d_in[3];
    const float* qnw   = (const float*)d_in[4];
    const float* knw   = (const float*)d_in[5];
    const float* pw    = (const float*)d_in[6];
    const float* pb    = (const float*)d_in[7];
    float* out = (float*)d_out;

    bf16* ws  = (bf16*)d_ws;
    bf16* xb  = ws + OFF_X;
    bf16* qwb = ws + OFF_QW;
    bf16* pwb = ws + OFF_PW;
    bf16* qkv = ws + OFF_QKV;
    bf16* vt  = (bf16*)d_out;   // scratch: Vt [B*H][D][N] = 12.6 MB of the
                                // 25.2 MB out buffer; proj overwrites it last.

    const int M = BB * NN;  // 8192

    // 0) cast MFMA operands to bf16
    convert3<<<1024, 256, 0, stream>>>(x, qkv_w, pw, ws);

    // 1) QKV projection + fused RMSNorm/RoPE/CEXP; v written transposed to Vt
    dim3 g1(3 * CC / 128, M / 128);
    gemm_qkv<<<g1, 256, 0, stream>>>(xb, qwb, qkv, vt, cosb, sinb, qnw, knw);

    // 2) Flash attention -> v-slice of qkv; in-lane P, no Ps LDS
    dim3 g4(BB * HH, NN / 128);
    flash_attn<<<g4, 512, 0, stream>>>(qkv, vt, qkv);

    // 3) Output projection (+fp32 bias) -> d_out
    dim3 g5(CC / 64, M / 128);
    gemm_proj<<<g5, 256, 0, stream>>>(qkv + 2 * CC, pwb, pb, out);
}

// Round 11
// 226.067 us; speedup vs baseline: 1.5016x; 1.0237x over previous
//
#include <hip/hip_runtime.h>
#include <hip/hip_bf16.h>

// Problem constants (B=4, N=2048, C=768, H=12, D=64)
#define BB 4
#define NN 2048
#define CC 768
#define HH 12
#define DD 64

typedef __bf16 bf16;
typedef __attribute__((ext_vector_type(8))) __bf16 bf16x8;
typedef __attribute__((ext_vector_type(4))) __bf16 bf16x4;
typedef __attribute__((ext_vector_type(4))) float f32x4;

// ---- workspace layout (bf16 elems) ----------------------------------------
#define SZ_X    (BB * NN * CC)              // 6291456
#define SZ_QKVW (3 * CC * CC)               // 1769472
#define SZ_PW   (CC * CC)                   // 589824
#define SZ_QKV  ((size_t)BB * NN * 3 * CC)  // 18874368

#define OFF_X    0
#define OFF_QW   (OFF_X + SZ_X)
#define OFF_PW   (OFF_QW + SZ_QKVW)
#define OFF_QKV  (OFF_PW + SZ_PW)           // end = 27525120 elems = 55.1 MB
// Vt [B*H][D][N] (12.6 MB) lives in d_out (25.2 MB f32 scratch until proj).
// NOTE (r11): Vt's n-dim is PERMUTED within each 64-key group:
//   key = mt*16 + quad*4 + r  ->  pos = (mt>>1)*32 + quad*8 + (mt&1)*4 + r
// so flash's in-lane P fragments contract against contiguous b128 V reads.

// Direct-to-LDS 16B DMA; source chunk XOR-swizzled to kill read conflicts.
__device__ __forceinline__ void async16(const bf16* g, bf16* l) {
    __builtin_amdgcn_global_load_lds(
        (const __attribute__((address_space(1))) unsigned int*)g,
        (__attribute__((address_space(3))) unsigned int*)l, 16, 0, 0);
}

// ---------------------------------------------------------------------------
__device__ __forceinline__ void cast8(const float* __restrict__ src,
                                      bf16* __restrict__ dst, int i) {
    f32x4 a = ((const f32x4*)src)[2 * i];
    f32x4 b = ((const f32x4*)src)[2 * i + 1];
    bf16x8 o;
#pragma unroll
    for (int j = 0; j < 4; ++j) { o[j] = (bf16)a[j]; o[j + 4] = (bf16)b[j]; }
    ((bf16x8*)dst)[i] = o;
}

__global__ __launch_bounds__(256) void convert3(
    const float* __restrict__ x, const float* __restrict__ qkvw,
    const float* __restrict__ pw, bf16* __restrict__ ws) {
    const int t = blockIdx.x * 256 + threadIdx.x;
    const int S = gridDim.x * 256;
    for (int i = t; i < SZ_X / 8;    i += S) cast8(x,    ws + OFF_X,  i);
    for (int i = t; i < SZ_QKVW / 8; i += S) cast8(qkvw, ws + OFF_QW, i);
    for (int i = t; i < SZ_PW / 8;   i += S) cast8(pw,   ws + OFF_PW, i);
}

// ---------------------------------------------------------------------------
// QKV GEMM with fused RMSNorm+RoPE epilogue + direct-transposed V store.
// r11 change: v-sector store permutes n within each 64-token group
// (quad*4+mt*16+r -> quad*8+(mt>>1)*32+(mt&1)*4+r) so flash's relabeled PV
// contraction reads V as contiguous b128 chunks (bank-conflict-free).
// ---------------------------------------------------------------------------
__global__ __launch_bounds__(256) void gemm_qkv(
    const bf16* __restrict__ A, const bf16* __restrict__ W,
    bf16* __restrict__ C, bf16* __restrict__ Vt,
    const float* __restrict__ cosb, const float* __restrict__ sinb,
    const float* __restrict__ qw, const float* __restrict__ kw) {
    __shared__ __align__(16) bf16 As[128 * 64];
    __shared__ __align__(16) bf16 Bs[128 * 64];
    const int tid  = threadIdx.x;
    const int wave = tid >> 6;
    const int lane = tid & 63;
    const int quad = lane >> 4;
    const int l16  = lane & 15;
    const int m0 = blockIdx.y * 128;
    const int n0 = blockIdx.x * 128;
    const int wm = (wave >> 1) * 64;
    const int wn = (wave & 1) * 64;
    const int srow = lane >> 3;
    const int swz  = (lane & 7) ^ srow;
    const int K = CC;
    const int Nn = 3 * CC;

    f32x4 acc[4][4];
#pragma unroll
    for (int i = 0; i < 4; ++i)
#pragma unroll
        for (int j = 0; j < 4; ++j) acc[i][j] = (f32x4){0.f, 0.f, 0.f, 0.f};

    for (int k0 = 0; k0 < K; k0 += 64) {
#pragma unroll
        for (int i = 0; i < 4; ++i) {
            int row = i * 32 + wave * 8 + srow;
            async16(A + (size_t)(m0 + row) * CC + k0 + swz * 8,
                    &As[(i * 32 + wave * 8) * 64]);
            async16(W + (size_t)(n0 + row) * K + k0 + swz * 8,
                    &Bs[(i * 32 + wave * 8) * 64]);
        }
        __syncthreads();
#pragma unroll
        for (int kk = 0; kk < 2; ++kk) {
            const int slot = ((kk * 4 + quad) ^ (l16 & 7)) * 8;
            bf16x8 af[4], bf[4];
#pragma unroll
            for (int mt = 0; mt < 4; ++mt)
                af[mt] = *(const bf16x8*)(&As[(wm + mt * 16 + l16) * 64 + slot]);
#pragma unroll
            for (int nt = 0; nt < 4; ++nt)
                bf[nt] = *(const bf16x8*)(&Bs[(wn + nt * 16 + l16) * 64 + slot]);
#pragma unroll
            for (int mt = 0; mt < 4; ++mt)
#pragma unroll
                for (int nt = 0; nt < 4; ++nt)
                    acc[mt][nt] = __builtin_amdgcn_mfma_f32_16x16x32_bf16(
                        af[mt], bf[nt], acc[mt][nt], 0, 0, 0);
        }
        __syncthreads();
    }

    const int colblk = n0 + wn;          // 64-aligned; one head of q/k/v
    const int sector = colblk / CC;      // 0=q, 1=k, 2=v
    if (sector == 2) {
        // v: transposed + key-permuted store straight to Vt[bh][d][pos].
        const int head = (colblk >> 6) - 24;
        const int btok = m0 + wm;
        const int bh   = (btok >> 11) * HH + head;
        const int nloc = btok & (NN - 1);
#pragma unroll
        for (int nt = 0; nt < 4; ++nt) {
            const int d = nt * 16 + l16;
            bf16* dst = Vt + ((size_t)bh * DD + d) * NN + nloc + quad * 8;
#pragma unroll
            for (int mt = 0; mt < 4; ++mt) {
                bf16x4 pk;
#pragma unroll
                for (int r = 0; r < 4; ++r) pk[r] = (bf16)acc[mt][nt][r];
                // pos offset: (mt>>1)*32 + (mt&1)*4
                *(bf16x4*)(dst + (mt >> 1) * 32 + (mt & 1) * 4) = pk;
            }
        }
    } else {
        const float* wp = (sector == 0) ? qw : kw;
        const float qs = (sector == 0) ? 0.18033688f : 1.0f;  // CEXP fold
        float wv[4];
#pragma unroll
        for (int nt = 0; nt < 4; ++nt) wv[nt] = wp[nt * 16 + l16];
#pragma unroll
        for (int mt = 0; mt < 4; ++mt)
#pragma unroll
            for (int r = 0; r < 4; ++r) {
                const int row = m0 + wm + mt * 16 + quad * 4 + r;
                const int n   = row & (NN - 1);
                float v[4];
#pragma unroll
                for (int nt = 0; nt < 4; ++nt) v[nt] = acc[mt][nt][r];
                float ss = v[0] * v[0] + v[1] * v[1] + v[2] * v[2] + v[3] * v[3];
                ss += __shfl_xor(ss, 1, 64);
                ss += __shfl_xor(ss, 2, 64);
                ss += __shfl_xor(ss, 4, 64);
                ss += __shfl_xor(ss, 8, 64);
                const float rn = rsqrtf(ss * (1.0f / 64.0f) + 1e-6f);
#pragma unroll
                for (int nt = 0; nt < 4; ++nt) v[nt] *= rn * wv[nt];
                const float c0 = cosb[n * 32 + l16];
                const float c1 = cosb[n * 32 + 16 + l16];
                const float s0 = sinb[n * 32 + l16];
                const float s1 = sinb[n * 32 + 16 + l16];
                float y[4];
                y[0] = v[0] * c0 - v[2] * s0;
                y[1] = v[1] * c1 - v[3] * s1;
                y[2] = v[2] * c0 + v[0] * s0;
                y[3] = v[3] * c1 + v[1] * s1;
#pragma unroll
                for (int nt = 0; nt < 4; ++nt) {
                    int col = colblk + nt * 16 + l16;
                    C[(size_t)row * Nn + col] = (bf16)(y[nt] * qs);
                }
            }
    }
}

// ---------------------------------------------------------------------------
// Output projection GEMM, 128x64 tiles (verified round 5, unchanged).
// ---------------------------------------------------------------------------
__global__ __launch_bounds__(256) void gemm_proj(
    const bf16* __restrict__ A, const bf16* __restrict__ W,
    const float* __restrict__ bias, float* __restrict__ C) {
    __shared__ __align__(16) bf16 As[128 * 64];
    __shared__ __align__(16) bf16 Bs[64 * 64];
    const int tid  = threadIdx.x;
    const int wave = tid >> 6;
    const int lane = tid & 63;
    const int quad = lane >> 4;
    const int l16  = lane & 15;
    const int m0 = blockIdx.y * 128;
    const int n0 = blockIdx.x * 64;
    const int wm = (wave >> 1) * 64;
    const int wn = (wave & 1) * 32;
    const int srow = lane >> 3;
    const int swz  = (lane & 7) ^ srow;
    const int lda = 3 * CC;
    const int K = CC;

    f32x4 acc[4][2];
#pragma unroll
    for (int i = 0; i < 4; ++i)
#pragma unroll
        for (int j = 0; j < 2; ++j) acc[i][j] = (f32x4){0.f, 0.f, 0.f, 0.f};

    for (int k0 = 0; k0 < K; k0 += 64) {
#pragma unroll
        for (int i = 0; i < 4; ++i) {
            int row = i * 32 + wave * 8 + srow;
            async16(A + (size_t)(m0 + row) * lda + k0 + swz * 8,
                    &As[(i * 32 + wave * 8) * 64]);
        }
#pragma unroll
        for (int i = 0; i < 2; ++i) {
            int row = i * 32 + wave * 8 + srow;
            async16(W + (size_t)(n0 + row) * K + k0 + swz * 8,
                    &Bs[(i * 32 + wave * 8) * 64]);
        }
        __syncthreads();
#pragma unroll
        for (int kk = 0; kk < 2; ++kk) {
            const int slot = ((kk * 4 + quad) ^ (l16 & 7)) * 8;
            bf16x8 af[4], bf[2];
#pragma unroll
            for (int mt = 0; mt < 4; ++mt)
                af[mt] = *(const bf16x8*)(&As[(wm + mt * 16 + l16) * 64 + slot]);
#pragma unroll
            for (int nt = 0; nt < 2; ++nt)
                bf[nt] = *(const bf16x8*)(&Bs[(wn + nt * 16 + l16) * 64 + slot]);
#pragma unroll
            for (int mt = 0; mt < 4; ++mt)
#pragma unroll
                for (int nt = 0; nt < 2; ++nt)
                    acc[mt][nt] = __builtin_amdgcn_mfma_f32_16x16x32_bf16(
                        af[mt], bf[nt], acc[mt][nt], 0, 0, 0);
        }
        __syncthreads();
    }
#pragma unroll
    for (int mt = 0; mt < 4; ++mt)
#pragma unroll
        for (int nt = 0; nt < 2; ++nt)
#pragma unroll
            for (int r = 0; r < 4; ++r) {
                int row = m0 + wm + mt * 16 + quad * 4 + r;
                int col = n0 + wn + nt * 16 + l16;
                C[(size_t)row * CC + col] = acc[mt][nt][r] + bias[col];
            }
}

// ---------------------------------------------------------------------------
// Flash attention, round-11: round-6 shape (8 waves x 16q, 512 thr) with the
// Ps LDS round-trip eliminated (in-lane P fragments, round-10 mechanism) AND
// conflict-free V reads: V arrives key-permuted from gemm_qkv, so the PV
// B-fragments are the ORIGINAL 2x ds_read_b128 at chunks (quad^r7) and
// ((quad+4)^r7) — the r10 4x b64 sub-offset reads (bank conflicts 4.7M ->
// 12.6M) are gone.  Per wave/tile DS ops vs round-6: -4 ds_write, -2
// ds_read_b128, -lgkmcnt(0) drain (~25% of the saturated DS pipe per the
// r9 ablation model).  LDS 16.4K, Occ ~53%.
// ---------------------------------------------------------------------------
__global__ __launch_bounds__(512) void flash_attn(
    const bf16* __restrict__ qkv, const bf16* __restrict__ Vt,
    bf16* __restrict__ Oqkv) {
    __shared__ __align__(16) bf16 Ks[64 * 64];       // [key][d] swizzled
    __shared__ __align__(16) bf16 Vs[64 * 64];       // [d][pos] swizzled
    const int tid  = threadIdx.x;
    const int wave = tid >> 6;
    const int lane = tid & 63;
    const int quad = lane >> 4;
    const int l16  = lane & 15;
    const int r7   = l16 & 7;
    const int bh = blockIdx.x;
    const int qt = blockIdx.y;
    const int b = bh / HH, h = bh % HH;
    const size_t rs = 3 * CC;
    const bf16* Qb  = qkv + (size_t)b * NN * rs + h * DD;
    const bf16* Kb  = Qb + CC;
    const bf16* Vtb = Vt + (size_t)bh * DD * NN;

    bf16x8 qf[2];
    {
        const int qrow = qt * 128 + wave * 16 + l16;
#pragma unroll
        for (int hf = 0; hf < 2; ++hf)
            qf[hf] = *(const bf16x8*)(Qb + (size_t)qrow * rs + hf * 32 + quad * 8);
    }

    f32x4 accO[4];
#pragma unroll
    for (int i = 0; i < 4; ++i) accO[i] = (f32x4){0.f, 0.f, 0.f, 0.f};
    float lsum = 0.f;

    const int srow = lane >> 3;
    const int swz  = (lane & 7) ^ srow;
    const int strow = wave * 8 + srow;

    for (int kt = 0; kt < NN / 64; ++kt) {
        async16(Kb + (size_t)(kt * 64 + strow) * rs + swz * 8,
                &Ks[(wave * 8) * 64]);
        async16(Vtb + (size_t)strow * NN + kt * 64 + swz * 8,
                &Vs[(wave * 8) * 64]);
        __syncthreads();

        // S^T = (Q K^T)^T via swapped operands; scores already exp2-domain
        f32x4 s[4];
#pragma unroll
        for (int nt = 0; nt < 4; ++nt) {
            const int row = nt * 16 + l16;
            bf16x8 kf0 = *(const bf16x8*)(&Ks[row * 64 + (quad ^ r7) * 8]);
            bf16x8 kf1 = *(const bf16x8*)(&Ks[row * 64 + ((quad + 4) ^ r7) * 8]);
            f32x4 z = (f32x4){0.f, 0.f, 0.f, 0.f};
            z = __builtin_amdgcn_mfma_f32_16x16x32_bf16(kf0, qf[0], z, 0, 0, 0);
            s[nt] = __builtin_amdgcn_mfma_f32_16x16x32_bf16(kf1, qf[1], z, 0, 0, 0);
        }

        // p = exp2(s); pack IN-LANE into the two PV A-fragments:
        //   pfa[j] = p[j>>2][j&3]      (keys 0..31 in relabeled order)
        //   pfb[j] = p[2+(j>>2)][j&3]  (keys 32..63)
        bf16x8 pfa, pfb;
#pragma unroll
        for (int nt = 0; nt < 4; ++nt)
#pragma unroll
            for (int r = 0; r < 4; ++r) {
                float pv = __builtin_amdgcn_exp2f(s[nt][r]);
                lsum += pv;
                if (nt < 2) pfa[nt * 4 + r] = (bf16)pv;
                else        pfb[(nt - 2) * 4 + r] = (bf16)pv;
            }

        // PV: V is key-permuted at the source, so fragment chunks are the
        // contiguous b128s at global chunks quad (pfa) and quad+4 (pfb).
#pragma unroll
        for (int nt = 0; nt < 4; ++nt) {
            const int rowd = nt * 16 + l16;
            bf16x8 vf0 = *(const bf16x8*)(&Vs[rowd * 64 + (quad ^ r7) * 8]);
            bf16x8 vf1 = *(const bf16x8*)(&Vs[rowd * 64 + ((quad + 4) ^ r7) * 8]);
            accO[nt] = __builtin_amdgcn_mfma_f32_16x16x32_bf16(pfa, vf0, accO[nt], 0, 0, 0);
            accO[nt] = __builtin_amdgcn_mfma_f32_16x16x32_bf16(pfb, vf1, accO[nt], 0, 0, 0);
        }
        __syncthreads();
    }

    // lsum: reduce over the 4 quads sharing l16 (lane's q = l16)
    lsum += __shfl_xor(lsum, 16, 64);
    lsum += __shfl_xor(lsum, 32, 64);

    // epilogue: accO row q = quad*4+r; fetch 1/lsum from lane quad*4+r
#pragma unroll
    for (int r = 0; r < 4; ++r) {
        float inv = 1.0f / __shfl(lsum, quad * 4 + r, 64);
        int n = qt * 128 + wave * 16 + quad * 4 + r;
#pragma unroll
        for (int nt = 0; nt < 4; ++nt) {
            int col = h * DD + nt * 16 + l16;
            Oqkv[(size_t)(b * NN + n) * rs + 2 * CC + col] = (bf16)(accO[nt][r] * inv);
        }
    }
}

// ---------------------------------------------------------------------------
extern "C" void kernel_launch(void* const* d_in, const int* in_sizes, int n_in,
                              void* d_out, int out_size, void* d_ws, size_t ws_size,
                              hipStream_t stream) {
    const float* x     = (const float*)d_in[0];
    const float* cosb  = (const float*)d_in[1];
    const float* sinb  = (const float*)d_in[2];
    const float* qkv_w = (const float*)d_in[3];
    const float* qnw   = (const float*)d_in[4];
    const float* knw   = (const float*)d_in[5];
    const float* pw    = (const float*)d_in[6];
    const float* pb    = (const float*)d_in[7];
    float* out = (float*)d_out;

    bf16* ws  = (bf16*)d_ws;
    bf16* xb  = ws + OFF_X;
    bf16* qwb = ws + OFF_QW;
    bf16* pwb = ws + OFF_PW;
    bf16* qkv = ws + OFF_QKV;
    bf16* vt  = (bf16*)d_out;   // scratch: Vt [B*H][D][N] = 12.6 MB of the
                                // 25.2 MB out buffer; proj overwrites it last.

    const int M = BB * NN;  // 8192

    // 0) cast MFMA operands to bf16
    convert3<<<1024, 256, 0, stream>>>(x, qkv_w, pw, ws);

    // 1) QKV projection + fused RMSNorm/RoPE/CEXP; v written transposed and
    //    key-permuted to Vt
    dim3 g1(3 * CC / 128, M / 128);
    gemm_qkv<<<g1, 256, 0, stream>>>(xb, qwb, qkv, vt, cosb, sinb, qnw, knw);

    // 2) Flash attention -> v-slice of qkv; in-lane P, conflict-free b128 V
    dim3 g4(BB * HH, NN / 128);
    flash_attn<<<g4, 512, 0, stream>>>(qkv, vt, qkv);

    // 3) Output projection (+fp32 bias) -> d_out
    dim3 g5(CC / 64, M / 128);
    gemm_proj<<<g5, 256, 0, stream>>>(qkv + 2 * CC, pwb, pb, out);
}

// Round 12
// 224.331 us; speedup vs baseline: 1.5132x; 1.0077x over previous
//
#include <hip/hip_runtime.h>
#include <hip/hip_bf16.h>

// Problem constants (B=4, N=2048, C=768, H=12, D=64)
#define BB 4
#define NN 2048
#define CC 768
#define HH 12
#define DD 64

typedef __bf16 bf16;
typedef __attribute__((ext_vector_type(8))) __bf16 bf16x8;
typedef __attribute__((ext_vector_type(4))) __bf16 bf16x4;
typedef __attribute__((ext_vector_type(4))) float f32x4;

// ---- workspace layout (bf16 elems) ----------------------------------------
#define SZ_X    (BB * NN * CC)              // 6291456
#define SZ_QKVW (3 * CC * CC)               // 1769472
#define SZ_PW   (CC * CC)                   // 589824
#define SZ_QKV  ((size_t)BB * NN * 3 * CC)  // 18874368

#define OFF_X    0
#define OFF_QW   (OFF_X + SZ_X)
#define OFF_PW   (OFF_QW + SZ_QKVW)
#define OFF_QKV  (OFF_PW + SZ_PW)           // end = 27525120 elems = 55.1 MB
// Vt [B*H][D][N] (12.6 MB) lives in d_out (25.2 MB f32 scratch until proj).
// Vt's n-dim is PERMUTED within each 64-key group (r11, verified):
//   key = mt*16 + quad*4 + r  ->  pos = (mt>>1)*32 + quad*8 + (mt&1)*4 + r
// so flash's in-lane P fragments contract against contiguous b128 V reads.

// Direct-to-LDS 16B DMA; source chunk XOR-swizzled to kill read conflicts.
__device__ __forceinline__ void async16(const bf16* g, bf16* l) {
    __builtin_amdgcn_global_load_lds(
        (const __attribute__((address_space(1))) unsigned int*)g,
        (__attribute__((address_space(3))) unsigned int*)l, 16, 0, 0);
}

// ---------------------------------------------------------------------------
__device__ __forceinline__ void cast8(const float* __restrict__ src,
                                      bf16* __restrict__ dst, int i) {
    f32x4 a = ((const f32x4*)src)[2 * i];
    f32x4 b = ((const f32x4*)src)[2 * i + 1];
    bf16x8 o;
#pragma unroll
    for (int j = 0; j < 4; ++j) { o[j] = (bf16)a[j]; o[j + 4] = (bf16)b[j]; }
    ((bf16x8*)dst)[i] = o;
}

__global__ __launch_bounds__(256) void convert3(
    const float* __restrict__ x, const float* __restrict__ qkvw,
    const float* __restrict__ pw, bf16* __restrict__ ws) {
    const int t = blockIdx.x * 256 + threadIdx.x;
    const int S = gridDim.x * 256;
    for (int i = t; i < SZ_X / 8;    i += S) cast8(x,    ws + OFF_X,  i);
    for (int i = t; i < SZ_QKVW / 8; i += S) cast8(qkvw, ws + OFF_QW, i);
    for (int i = t; i < SZ_PW / 8;   i += S) cast8(pw,   ws + OFF_PW, i);
}

// ---------------------------------------------------------------------------
// QKV GEMM with fused RMSNorm+RoPE epilogue + direct-transposed, key-permuted
// V store (verified rounds 4-5, 11; unchanged).
// ---------------------------------------------------------------------------
__global__ __launch_bounds__(256) void gemm_qkv(
    const bf16* __restrict__ A, const bf16* __restrict__ W,
    bf16* __restrict__ C, bf16* __restrict__ Vt,
    const float* __restrict__ cosb, const float* __restrict__ sinb,
    const float* __restrict__ qw, const float* __restrict__ kw) {
    __shared__ __align__(16) bf16 As[128 * 64];
    __shared__ __align__(16) bf16 Bs[128 * 64];
    const int tid  = threadIdx.x;
    const int wave = tid >> 6;
    const int lane = tid & 63;
    const int quad = lane >> 4;
    const int l16  = lane & 15;
    const int m0 = blockIdx.y * 128;
    const int n0 = blockIdx.x * 128;
    const int wm = (wave >> 1) * 64;
    const int wn = (wave & 1) * 64;
    const int srow = lane >> 3;
    const int swz  = (lane & 7) ^ srow;
    const int K = CC;
    const int Nn = 3 * CC;

    f32x4 acc[4][4];
#pragma unroll
    for (int i = 0; i < 4; ++i)
#pragma unroll
        for (int j = 0; j < 4; ++j) acc[i][j] = (f32x4){0.f, 0.f, 0.f, 0.f};

    for (int k0 = 0; k0 < K; k0 += 64) {
#pragma unroll
        for (int i = 0; i < 4; ++i) {
            int row = i * 32 + wave * 8 + srow;
            async16(A + (size_t)(m0 + row) * CC + k0 + swz * 8,
                    &As[(i * 32 + wave * 8) * 64]);
            async16(W + (size_t)(n0 + row) * K + k0 + swz * 8,
                    &Bs[(i * 32 + wave * 8) * 64]);
        }
        __syncthreads();
#pragma unroll
        for (int kk = 0; kk < 2; ++kk) {
            const int slot = ((kk * 4 + quad) ^ (l16 & 7)) * 8;
            bf16x8 af[4], bf[4];
#pragma unroll
            for (int mt = 0; mt < 4; ++mt)
                af[mt] = *(const bf16x8*)(&As[(wm + mt * 16 + l16) * 64 + slot]);
#pragma unroll
            for (int nt = 0; nt < 4; ++nt)
                bf[nt] = *(const bf16x8*)(&Bs[(wn + nt * 16 + l16) * 64 + slot]);
#pragma unroll
            for (int mt = 0; mt < 4; ++mt)
#pragma unroll
                for (int nt = 0; nt < 4; ++nt)
                    acc[mt][nt] = __builtin_amdgcn_mfma_f32_16x16x32_bf16(
                        af[mt], bf[nt], acc[mt][nt], 0, 0, 0);
        }
        __syncthreads();
    }

    const int colblk = n0 + wn;          // 64-aligned; one head of q/k/v
    const int sector = colblk / CC;      // 0=q, 1=k, 2=v
    if (sector == 2) {
        // v: transposed + key-permuted store straight to Vt[bh][d][pos].
        const int head = (colblk >> 6) - 24;
        const int btok = m0 + wm;
        const int bh   = (btok >> 11) * HH + head;
        const int nloc = btok & (NN - 1);
#pragma unroll
        for (int nt = 0; nt < 4; ++nt) {
            const int d = nt * 16 + l16;
            bf16* dst = Vt + ((size_t)bh * DD + d) * NN + nloc + quad * 8;
#pragma unroll
            for (int mt = 0; mt < 4; ++mt) {
                bf16x4 pk;
#pragma unroll
                for (int r = 0; r < 4; ++r) pk[r] = (bf16)acc[mt][nt][r];
                // pos offset: (mt>>1)*32 + (mt&1)*4
                *(bf16x4*)(dst + (mt >> 1) * 32 + (mt & 1) * 4) = pk;
            }
        }
    } else {
        const float* wp = (sector == 0) ? qw : kw;
        const float qs = (sector == 0) ? 0.18033688f : 1.0f;  // CEXP fold
        float wv[4];
#pragma unroll
        for (int nt = 0; nt < 4; ++nt) wv[nt] = wp[nt * 16 + l16];
#pragma unroll
        for (int mt = 0; mt < 4; ++mt)
#pragma unroll
            for (int r = 0; r < 4; ++r) {
                const int row = m0 + wm + mt * 16 + quad * 4 + r;
                const int n   = row & (NN - 1);
                float v[4];
#pragma unroll
                for (int nt = 0; nt < 4; ++nt) v[nt] = acc[mt][nt][r];
                float ss = v[0] * v[0] + v[1] * v[1] + v[2] * v[2] + v[3] * v[3];
                ss += __shfl_xor(ss, 1, 64);
                ss += __shfl_xor(ss, 2, 64);
                ss += __shfl_xor(ss, 4, 64);
                ss += __shfl_xor(ss, 8, 64);
                const float rn = rsqrtf(ss * (1.0f / 64.0f) + 1e-6f);
#pragma unroll
                for (int nt = 0; nt < 4; ++nt) v[nt] *= rn * wv[nt];
                const float c0 = cosb[n * 32 + l16];
                const float c1 = cosb[n * 32 + 16 + l16];
                const float s0 = sinb[n * 32 + l16];
                const float s1 = sinb[n * 32 + 16 + l16];
                float y[4];
                y[0] = v[0] * c0 - v[2] * s0;
                y[1] = v[1] * c1 - v[3] * s1;
                y[2] = v[2] * c0 + v[0] * s0;
                y[3] = v[3] * c1 + v[1] * s1;
#pragma unroll
                for (int nt = 0; nt < 4; ++nt) {
                    int col = colblk + nt * 16 + l16;
                    C[(size_t)row * Nn + col] = (bf16)(y[nt] * qs);
                }
            }
    }
}

// ---------------------------------------------------------------------------
// Output projection GEMM, 128x64 tiles (verified round 5, unchanged).
// ---------------------------------------------------------------------------
__global__ __launch_bounds__(256) void gemm_proj(
    const bf16* __restrict__ A, const bf16* __restrict__ W,
    const float* __restrict__ bias, float* __restrict__ C) {
    __shared__ __align__(16) bf16 As[128 * 64];
    __shared__ __align__(16) bf16 Bs[64 * 64];
    const int tid  = threadIdx.x;
    const int wave = tid >> 6;
    const int lane = tid & 63;
    const int quad = lane >> 4;
    const int l16  = lane & 15;
    const int m0 = blockIdx.y * 128;
    const int n0 = blockIdx.x * 64;
    const int wm = (wave >> 1) * 64;
    const int wn = (wave & 1) * 32;
    const int srow = lane >> 3;
    const int swz  = (lane & 7) ^ srow;
    const int lda = 3 * CC;
    const int K = CC;

    f32x4 acc[4][2];
#pragma unroll
    for (int i = 0; i < 4; ++i)
#pragma unroll
        for (int j = 0; j < 2; ++j) acc[i][j] = (f32x4){0.f, 0.f, 0.f, 0.f};

    for (int k0 = 0; k0 < K; k0 += 64) {
#pragma unroll
        for (int i = 0; i < 4; ++i) {
            int row = i * 32 + wave * 8 + srow;
            async16(A + (size_t)(m0 + row) * lda + k0 + swz * 8,
                    &As[(i * 32 + wave * 8) * 64]);
        }
#pragma unroll
        for (int i = 0; i < 2; ++i) {
            int row = i * 32 + wave * 8 + srow;
            async16(W + (size_t)(n0 + row) * K + k0 + swz * 8,
                    &Bs[(i * 32 + wave * 8) * 64]);
        }
        __syncthreads();
#pragma unroll
        for (int kk = 0; kk < 2; ++kk) {
            const int slot = ((kk * 4 + quad) ^ (l16 & 7)) * 8;
            bf16x8 af[4], bf[2];
#pragma unroll
            for (int mt = 0; mt < 4; ++mt)
                af[mt] = *(const bf16x8*)(&As[(wm + mt * 16 + l16) * 64 + slot]);
#pragma unroll
            for (int nt = 0; nt < 2; ++nt)
                bf[nt] = *(const bf16x8*)(&Bs[(wn + nt * 16 + l16) * 64 + slot]);
#pragma unroll
            for (int mt = 0; mt < 4; ++mt)
#pragma unroll
                for (int nt = 0; nt < 2; ++nt)
                    acc[mt][nt] = __builtin_amdgcn_mfma_f32_16x16x32_bf16(
                        af[mt], bf[nt], acc[mt][nt], 0, 0, 0);
        }
        __syncthreads();
    }
#pragma unroll
    for (int mt = 0; mt < 4; ++mt)
#pragma unroll
        for (int nt = 0; nt < 2; ++nt)
#pragma unroll
            for (int r = 0; r < 4; ++r) {
                int row = m0 + wm + mt * 16 + quad * 4 + r;
                int col = n0 + wn + nt * 16 + l16;
                C[(size_t)row * CC + col] = acc[mt][nt][r] + bias[col];
            }
}

// ---------------------------------------------------------------------------
// Flash attention, round-12: qw=32 kt-split + Ps-free body.
// DS model (validated r9/r11): K/V fragment reads are 16 KB/wave/tile
// independent of q-width -> qw=32 halves reads per unit work.  r7's kt-split
// (verified) provides the occupancy qw=32 lacks: 8 waves = 4 q-groups x 2
// kt-halves, each wave computes 16 of 32 tiles.  Wave-tiles 196k -> 98k;
// DS demand ~31us reads + ~7us staging.  Body = r11's in-lane P fragments +
// key-permuted-V b128 reads (bank-conflict-free, verified).  LDS = 2x(K,V)
// = 32 KB (Ps gone; r7's 68KB capped blocks, this doesn't): 3 blocks/CU x
// 512 thr = 24 waves/CU.  1 barrier/tile (2 per 2-tile step).  Epilogue:
// linear exp2-domain combine of kt-halves (r7, verified), two f-passes
// through the dead Ks buffer (17.9 KB < 32 KB).
// ---------------------------------------------------------------------------
__global__ __launch_bounds__(512) void flash_attn(
    const bf16* __restrict__ qkv, const bf16* __restrict__ Vt,
    bf16* __restrict__ Oqkv) {
    __shared__ __align__(16) bf16 Ks[2][64 * 64];    // [tile][key][d] swizzled
    __shared__ __align__(16) bf16 Vs[2][64 * 64];    // [tile][d][pos] swizzled
    const int tid  = threadIdx.x;
    const int wave = tid >> 6;          // 0..7
    const int w4   = wave & 3;          // q-group (32 rows)
    const int half = wave >> 2;         // kt parity this wave computes
    const int lane = tid & 63;
    const int quad = lane >> 4;
    const int l16  = lane & 15;
    const int r7   = l16 & 7;
    const int bh = blockIdx.x;
    const int qt = blockIdx.y;
    const int b = bh / HH, h = bh % HH;
    const size_t rs = 3 * CC;
    const bf16* Qb  = qkv + (size_t)b * NN * rs + h * DD;
    const bf16* Kb  = Qb + CC;
    const bf16* Vtb = Vt + (size_t)bh * DD * NN;

    bf16x8 qf[2][2];
#pragma unroll
    for (int f = 0; f < 2; ++f) {
        const int qrow = qt * 128 + w4 * 32 + f * 16 + l16;
#pragma unroll
        for (int hf = 0; hf < 2; ++hf)
            qf[f][hf] = *(const bf16x8*)(Qb + (size_t)qrow * rs + hf * 32 + quad * 8);
    }

    f32x4 accO[2][4];
#pragma unroll
    for (int f = 0; f < 2; ++f)
#pragma unroll
        for (int i = 0; i < 4; ++i) accO[f][i] = (f32x4){0.f, 0.f, 0.f, 0.f};
    float lsum[2] = {0.f, 0.f};

    const int srow  = lane >> 3;
    const int swz   = (lane & 7) ^ srow;
    const int strow = wave * 8 + srow;      // staging rows: 8 per wave

    for (int step = 0; step < NN / 128; ++step) {
        const int t0 = step * 2;
        // stage BOTH tiles of the pair (4 DMA issues per wave, 8 rows each)
        async16(Kb + (size_t)(t0 * 64 + strow) * rs + swz * 8,
                &Ks[0][(wave * 8) * 64]);
        async16(Kb + (size_t)((t0 + 1) * 64 + strow) * rs + swz * 8,
                &Ks[1][(wave * 8) * 64]);
        async16(Vtb + (size_t)strow * NN + t0 * 64 + swz * 8,
                &Vs[0][(wave * 8) * 64]);
        async16(Vtb + (size_t)strow * NN + (t0 + 1) * 64 + swz * 8,
                &Vs[1][(wave * 8) * 64]);
        __syncthreads();

        const bf16* Kc = Ks[half];
        const bf16* Vc = Vs[half];

        // S^T = (Q K^T)^T via swapped operands; scores already exp2-domain
        f32x4 s[2][4];
#pragma unroll
        for (int nt = 0; nt < 4; ++nt) {
            const int row = nt * 16 + l16;
            bf16x8 kf0 = *(const bf16x8*)(&Kc[row * 64 + (quad ^ r7) * 8]);
            bf16x8 kf1 = *(const bf16x8*)(&Kc[row * 64 + ((quad + 4) ^ r7) * 8]);
#pragma unroll
            for (int f = 0; f < 2; ++f) {
                f32x4 z = (f32x4){0.f, 0.f, 0.f, 0.f};
                z = __builtin_amdgcn_mfma_f32_16x16x32_bf16(kf0, qf[f][0], z, 0, 0, 0);
                s[f][nt] = __builtin_amdgcn_mfma_f32_16x16x32_bf16(kf1, qf[f][1], z, 0, 0, 0);
            }
        }

        // p = exp2(s); pack IN-LANE into PV A-fragments (keys relabeled to
        // match the source-permuted V)
        bf16x8 pfa[2], pfb[2];
#pragma unroll
        for (int f = 0; f < 2; ++f)
#pragma unroll
            for (int nt = 0; nt < 4; ++nt)
#pragma unroll
                for (int r = 0; r < 4; ++r) {
                    float pv = __builtin_amdgcn_exp2f(s[f][nt][r]);
                    lsum[f] += pv;
                    if (nt < 2) pfa[f][nt * 4 + r] = (bf16)pv;
                    else        pfb[f][(nt - 2) * 4 + r] = (bf16)pv;
                }

        // PV: contiguous b128 V fragments (conflict-free), shared across f
#pragma unroll
        for (int nt = 0; nt < 4; ++nt) {
            const int rowd = nt * 16 + l16;
            bf16x8 vf0 = *(const bf16x8*)(&Vc[rowd * 64 + (quad ^ r7) * 8]);
            bf16x8 vf1 = *(const bf16x8*)(&Vc[rowd * 64 + ((quad + 4) ^ r7) * 8]);
#pragma unroll
            for (int f = 0; f < 2; ++f) {
                accO[f][nt] = __builtin_amdgcn_mfma_f32_16x16x32_bf16(pfa[f], vf0, accO[f][nt], 0, 0, 0);
                accO[f][nt] = __builtin_amdgcn_mfma_f32_16x16x32_bf16(pfb[f], vf1, accO[f][nt], 0, 0, 0);
            }
        }
        __syncthreads();   // all waves done reading Ks/Vs before restage
    }

    // lsum: reduce over the 4 quads sharing l16 (lane's q = f*16+l16)
#pragma unroll
    for (int f = 0; f < 2; ++f) {
        lsum[f] += __shfl_xor(lsum[f], 16, 64);
        lsum[f] += __shfl_xor(lsum[f], 32, 64);
    }

    // ---- combine kt-halves (waves w and w+4 share q-rows); exp2-domain
    // partials are linearly combinable (r7, verified).  Two f-passes through
    // the dead Ks buffer: Osc[64][68] f32 + Ls[128] = 17.9 KB < 32 KB.
    float* Osc = (float*)&Ks[0][0];
    float* Ls  = Osc + 64 * 68;
#pragma unroll
    for (int f = 0; f < 2; ++f) {
        if (wave >= 4) {
            if (quad == 0) Ls[w4 * 32 + f * 16 + l16] = lsum[f];
#pragma unroll
            for (int nt = 0; nt < 4; ++nt)
#pragma unroll
                for (int r = 0; r < 4; ++r)
                    Osc[(w4 * 16 + quad * 4 + r) * 68 + nt * 16 + l16] =
                        accO[f][nt][r];
        }
        __syncthreads();
        if (wave < 4) {
            float lt = lsum[f] + Ls[w4 * 32 + f * 16 + l16];
#pragma unroll
            for (int nt = 0; nt < 4; ++nt)
#pragma unroll
                for (int r = 0; r < 4; ++r)
                    accO[f][nt][r] +=
                        Osc[(w4 * 16 + quad * 4 + r) * 68 + nt * 16 + l16];
#pragma unroll
            for (int r = 0; r < 4; ++r) {
                float inv = 1.0f / __shfl(lt, quad * 4 + r, 64);
                int n = qt * 128 + w4 * 32 + f * 16 + quad * 4 + r;
#pragma unroll
                for (int nt = 0; nt < 4; ++nt) {
                    int col = h * DD + nt * 16 + l16;
                    Oqkv[(size_t)(b * NN + n) * rs + 2 * CC + col] =
                        (bf16)(accO[f][nt][r] * inv);
                }
            }
        }
        __syncthreads();   // pass-f reads done before pass-(f+1) overwrites
    }
}

// ---------------------------------------------------------------------------
extern "C" void kernel_launch(void* const* d_in, const int* in_sizes, int n_in,
                              void* d_out, int out_size, void* d_ws, size_t ws_size,
                              hipStream_t stream) {
    const float* x     = (const float*)d_in[0];
    const float* cosb  = (const float*)d_in[1];
    const float* sinb  = (const float*)d_in[2];
    const float* qkv_w = (const float*)d_in[3];
    const float* qnw   = (const float*)d_in[4];
    const float* knw   = (const float*)d_in[5];
    const float* pw    = (const float*)d_in[6];
    const float* pb    = (const float*)d_in[7];
    float* out = (float*)d_out;

    bf16* ws  = (bf16*)d_ws;
    bf16* xb  = ws + OFF_X;
    bf16* qwb = ws + OFF_QW;
    bf16* pwb = ws + OFF_PW;
    bf16* qkv = ws + OFF_QKV;
    bf16* vt  = (bf16*)d_out;   // scratch: Vt [B*H][D][N] = 12.6 MB of the
                                // 25.2 MB out buffer; proj overwrites it last.

    const int M = BB * NN;  // 8192

    // 0) cast MFMA operands to bf16
    convert3<<<1024, 256, 0, stream>>>(x, qkv_w, pw, ws);

    // 1) QKV projection + fused RMSNorm/RoPE/CEXP; v written transposed and
    //    key-permuted to Vt
    dim3 g1(3 * CC / 128, M / 128);
    gemm_qkv<<<g1, 256, 0, stream>>>(xb, qwb, qkv, vt, cosb, sinb, qnw, knw);

    // 2) Flash attention -> v-slice of qkv; qw=32 kt-split, Ps-free
    dim3 g4(BB * HH, NN / 128);
    flash_attn<<<g4, 512, 0, stream>>>(qkv, vt, qkv);

    // 3) Output projection (+fp32 bias) -> d_out
    dim3 g5(CC / 64, M / 128);
    gemm_proj<<<g5, 256, 0, stream>>>(qkv + 2 * CC, pwb, pb, out);
}

// Round 13
// 218.679 us; speedup vs baseline: 1.5523x; 1.0258x over previous
//
#include <hip/hip_runtime.h>
#include <hip/hip_bf16.h>

// Problem constants (B=4, N=2048, C=768, H=12, D=64)
#define BB 4
#define NN 2048
#define CC 768
#define HH 12
#define DD 64

typedef __bf16 bf16;
typedef __attribute__((ext_vector_type(8))) __bf16 bf16x8;
typedef __attribute__((ext_vector_type(4))) __bf16 bf16x4;
typedef __attribute__((ext_vector_type(4))) float f32x4;

// ---- workspace layout (bf16 elems) ----------------------------------------
#define SZ_X    (BB * NN * CC)              // 6291456
#define SZ_QKVW (3 * CC * CC)               // 1769472
#define SZ_PW   (CC * CC)                   // 589824
#define SZ_QKV  ((size_t)BB * NN * 3 * CC)  // 18874368

#define OFF_X    0
#define OFF_QW   (OFF_X + SZ_X)
#define OFF_PW   (OFF_QW + SZ_QKVW)
#define OFF_QKV  (OFF_PW + SZ_PW)           // end = 27525120 elems = 55.1 MB
// Vt [B*H][D][N] (12.6 MB) lives in d_out (25.2 MB f32 scratch until proj).
// Vt's n-dim is PERMUTED within each 64-key group (r11, verified):
//   key = mt*16 + quad*4 + r  ->  pos = (mt>>1)*32 + quad*8 + (mt&1)*4 + r
// so flash's in-lane P fragments contract against contiguous b128 V reads.

// Direct-to-LDS 16B DMA; source chunk XOR-swizzled to kill read conflicts.
__device__ __forceinline__ void async16(const bf16* g, bf16* l) {
    __builtin_amdgcn_global_load_lds(
        (const __attribute__((address_space(1))) unsigned int*)g,
        (__attribute__((address_space(3))) unsigned int*)l, 16, 0, 0);
}

// ---------------------------------------------------------------------------
__device__ __forceinline__ void cast8(const float* __restrict__ src,
                                      bf16* __restrict__ dst, int i) {
    f32x4 a = ((const f32x4*)src)[2 * i];
    f32x4 b = ((const f32x4*)src)[2 * i + 1];
    bf16x8 o;
#pragma unroll
    for (int j = 0; j < 4; ++j) { o[j] = (bf16)a[j]; o[j + 4] = (bf16)b[j]; }
    ((bf16x8*)dst)[i] = o;
}

__global__ __launch_bounds__(256) void convert3(
    const float* __restrict__ x, const float* __restrict__ qkvw,
    const float* __restrict__ pw, bf16* __restrict__ ws) {
    const int t = blockIdx.x * 256 + threadIdx.x;
    const int S = gridDim.x * 256;
    for (int i = t; i < SZ_X / 8;    i += S) cast8(x,    ws + OFF_X,  i);
    for (int i = t; i < SZ_QKVW / 8; i += S) cast8(qkvw, ws + OFF_QW, i);
    for (int i = t; i < SZ_PW / 8;   i += S) cast8(pw,   ws + OFF_PW, i);
}

// ---------------------------------------------------------------------------
// QKV GEMM with fused RMSNorm+RoPE epilogue + direct-transposed, key-permuted
// V store (verified rounds 4-5, 11).  r13: 1D grid + T1 XCD-chunked swizzle
// (1152 blocks = 8 XCDs x 144; each XCD gets 8 m-panels x all 18 n-blocks,
// so A-row-panels are fetched once per XCD L2 instead of 8x).
// ---------------------------------------------------------------------------
__global__ __launch_bounds__(256) void gemm_qkv(
    const bf16* __restrict__ A, const bf16* __restrict__ W,
    bf16* __restrict__ C, bf16* __restrict__ Vt,
    const float* __restrict__ cosb, const float* __restrict__ sinb,
    const float* __restrict__ qw, const float* __restrict__ kw) {
    __shared__ __align__(16) bf16 As[128 * 64];
    __shared__ __align__(16) bf16 Bs[128 * 64];
    const int tid  = threadIdx.x;
    const int wave = tid >> 6;
    const int lane = tid & 63;
    const int quad = lane >> 4;
    const int l16  = lane & 15;
    // T1 XCD swizzle: consecutive hw block-ids round-robin across 8 XCDs;
    // remap so each XCD owns a contiguous chunk of the (m,n) ordering.
    const int id = blockIdx.x;                 // 0..1151
    const int w  = (id & 7) * 144 + (id >> 3); // bijective (1152 = 8*144)
    const int m0 = (w / 18) * 128;
    const int n0 = (w % 18) * 128;
    const int wm = (wave >> 1) * 64;
    const int wn = (wave & 1) * 64;
    const int srow = lane >> 3;
    const int swz  = (lane & 7) ^ srow;
    const int K = CC;
    const int Nn = 3 * CC;

    f32x4 acc[4][4];
#pragma unroll
    for (int i = 0; i < 4; ++i)
#pragma unroll
        for (int j = 0; j < 4; ++j) acc[i][j] = (f32x4){0.f, 0.f, 0.f, 0.f};

    for (int k0 = 0; k0 < K; k0 += 64) {
#pragma unroll
        for (int i = 0; i < 4; ++i) {
            int row = i * 32 + wave * 8 + srow;
            async16(A + (size_t)(m0 + row) * CC + k0 + swz * 8,
                    &As[(i * 32 + wave * 8) * 64]);
            async16(W + (size_t)(n0 + row) * K + k0 + swz * 8,
                    &Bs[(i * 32 + wave * 8) * 64]);
        }
        __syncthreads();
#pragma unroll
        for (int kk = 0; kk < 2; ++kk) {
            const int slot = ((kk * 4 + quad) ^ (l16 & 7)) * 8;
            bf16x8 af[4], bf[4];
#pragma unroll
            for (int mt = 0; mt < 4; ++mt)
                af[mt] = *(const bf16x8*)(&As[(wm + mt * 16 + l16) * 64 + slot]);
#pragma unroll
            for (int nt = 0; nt < 4; ++nt)
                bf[nt] = *(const bf16x8*)(&Bs[(wn + nt * 16 + l16) * 64 + slot]);
#pragma unroll
            for (int mt = 0; mt < 4; ++mt)
#pragma unroll
                for (int nt = 0; nt < 4; ++nt)
                    acc[mt][nt] = __builtin_amdgcn_mfma_f32_16x16x32_bf16(
                        af[mt], bf[nt], acc[mt][nt], 0, 0, 0);
        }
        __syncthreads();
    }

    const int colblk = n0 + wn;          // 64-aligned; one head of q/k/v
    const int sector = colblk / CC;      // 0=q, 1=k, 2=v
    if (sector == 2) {
        // v: transposed + key-permuted store straight to Vt[bh][d][pos].
        const int head = (colblk >> 6) - 24;
        const int btok = m0 + wm;
        const int bh   = (btok >> 11) * HH + head;
        const int nloc = btok & (NN - 1);
#pragma unroll
        for (int nt = 0; nt < 4; ++nt) {
            const int d = nt * 16 + l16;
            bf16* dst = Vt + ((size_t)bh * DD + d) * NN + nloc + quad * 8;
#pragma unroll
            for (int mt = 0; mt < 4; ++mt) {
                bf16x4 pk;
#pragma unroll
                for (int r = 0; r < 4; ++r) pk[r] = (bf16)acc[mt][nt][r];
                // pos offset: (mt>>1)*32 + (mt&1)*4
                *(bf16x4*)(dst + (mt >> 1) * 32 + (mt & 1) * 4) = pk;
            }
        }
    } else {
        const float* wp = (sector == 0) ? qw : kw;
        const float qs = (sector == 0) ? 0.18033688f : 1.0f;  // CEXP fold
        float wv[4];
#pragma unroll
        for (int nt = 0; nt < 4; ++nt) wv[nt] = wp[nt * 16 + l16];
#pragma unroll
        for (int mt = 0; mt < 4; ++mt)
#pragma unroll
            for (int r = 0; r < 4; ++r) {
                const int row = m0 + wm + mt * 16 + quad * 4 + r;
                const int n   = row & (NN - 1);
                float v[4];
#pragma unroll
                for (int nt = 0; nt < 4; ++nt) v[nt] = acc[mt][nt][r];
                float ss = v[0] * v[0] + v[1] * v[1] + v[2] * v[2] + v[3] * v[3];
                ss += __shfl_xor(ss, 1, 64);
                ss += __shfl_xor(ss, 2, 64);
                ss += __shfl_xor(ss, 4, 64);
                ss += __shfl_xor(ss, 8, 64);
                const float rn = rsqrtf(ss * (1.0f / 64.0f) + 1e-6f);
#pragma unroll
                for (int nt = 0; nt < 4; ++nt) v[nt] *= rn * wv[nt];
                const float c0 = cosb[n * 32 + l16];
                const float c1 = cosb[n * 32 + 16 + l16];
                const float s0 = sinb[n * 32 + l16];
                const float s1 = sinb[n * 32 + 16 + l16];
                float y[4];
                y[0] = v[0] * c0 - v[2] * s0;
                y[1] = v[1] * c1 - v[3] * s1;
                y[2] = v[2] * c0 + v[0] * s0;
                y[3] = v[3] * c1 + v[1] * s1;
#pragma unroll
                for (int nt = 0; nt < 4; ++nt) {
                    int col = colblk + nt * 16 + l16;
                    C[(size_t)row * Nn + col] = (bf16)(y[nt] * qs);
                }
            }
    }
}

// ---------------------------------------------------------------------------
// Output projection GEMM, 128x64 tiles (verified round 5).  r13: 1D grid +
// T1 XCD-chunked swizzle (768 = 8 x 96; A-panels read once per XCD L2,
// B (1.2 MB) L2-resident).
// ---------------------------------------------------------------------------
__global__ __launch_bounds__(256) void gemm_proj(
    const bf16* __restrict__ A, const bf16* __restrict__ W,
    const float* __restrict__ bias, float* __restrict__ C) {
    __shared__ __align__(16) bf16 As[128 * 64];
    __shared__ __align__(16) bf16 Bs[64 * 64];
    const int tid  = threadIdx.x;
    const int wave = tid >> 6;
    const int lane = tid & 63;
    const int quad = lane >> 4;
    const int l16  = lane & 15;
    const int id = blockIdx.x;                // 0..767
    const int w  = (id & 7) * 96 + (id >> 3); // bijective (768 = 8*96)
    const int m0 = (w / 12) * 128;
    const int n0 = (w % 12) * 64;
    const int wm = (wave >> 1) * 64;
    const int wn = (wave & 1) * 32;
    const int srow = lane >> 3;
    const int swz  = (lane & 7) ^ srow;
    const int lda = 3 * CC;
    const int K = CC;

    f32x4 acc[4][2];
#pragma unroll
    for (int i = 0; i < 4; ++i)
#pragma unroll
        for (int j = 0; j < 2; ++j) acc[i][j] = (f32x4){0.f, 0.f, 0.f, 0.f};

    for (int k0 = 0; k0 < K; k0 += 64) {
#pragma unroll
        for (int i = 0; i < 4; ++i) {
            int row = i * 32 + wave * 8 + srow;
            async16(A + (size_t)(m0 + row) * lda + k0 + swz * 8,
                    &As[(i * 32 + wave * 8) * 64]);
        }
#pragma unroll
        for (int i = 0; i < 2; ++i) {
            int row = i * 32 + wave * 8 + srow;
            async16(W + (size_t)(n0 + row) * K + k0 + swz * 8,
                    &Bs[(i * 32 + wave * 8) * 64]);
        }
        __syncthreads();
#pragma unroll
        for (int kk = 0; kk < 2; ++kk) {
            const int slot = ((kk * 4 + quad) ^ (l16 & 7)) * 8;
            bf16x8 af[4], bf[2];
#pragma unroll
            for (int mt = 0; mt < 4; ++mt)
                af[mt] = *(const bf16x8*)(&As[(wm + mt * 16 + l16) * 64 + slot]);
#pragma unroll
            for (int nt = 0; nt < 2; ++nt)
                bf[nt] = *(const bf16x8*)(&Bs[(wn + nt * 16 + l16) * 64 + slot]);
#pragma unroll
            for (int mt = 0; mt < 4; ++mt)
#pragma unroll
                for (int nt = 0; nt < 2; ++nt)
                    acc[mt][nt] = __builtin_amdgcn_mfma_f32_16x16x32_bf16(
                        af[mt], bf[nt], acc[mt][nt], 0, 0, 0);
        }
        __syncthreads();
    }
#pragma unroll
    for (int mt = 0; mt < 4; ++mt)
#pragma unroll
        for (int nt = 0; nt < 2; ++nt)
#pragma unroll
            for (int r = 0; r < 4; ++r) {
                int row = m0 + wm + mt * 16 + quad * 4 + r;
                int col = n0 + wn + nt * 16 + l16;
                C[(size_t)row * CC + col] = acc[mt][nt][r] + bias[col];
            }
}

// ---------------------------------------------------------------------------
// Flash attention — round-11 version restored VERBATIM (best measured:
// 61.8us = ds_read_b128 roofline, bank conflicts 0, Occ 46%).  8 waves x
// 16 q-rows, 512 thr, Ps-free in-lane P fragments + key-permuted V b128s.
// r12's qw=32 kt-split regressed (67.0us: Occ 32%, FETCH +40%) — reverted.
// ---------------------------------------------------------------------------
__global__ __launch_bounds__(512) void flash_attn(
    const bf16* __restrict__ qkv, const bf16* __restrict__ Vt,
    bf16* __restrict__ Oqkv) {
    __shared__ __align__(16) bf16 Ks[64 * 64];       // [key][d] swizzled
    __shared__ __align__(16) bf16 Vs[64 * 64];       // [d][pos] swizzled
    const int tid  = threadIdx.x;
    const int wave = tid >> 6;
    const int lane = tid & 63;
    const int quad = lane >> 4;
    const int l16  = lane & 15;
    const int r7   = l16 & 7;
    const int bh = blockIdx.x;
    const int qt = blockIdx.y;
    const int b = bh / HH, h = bh % HH;
    const size_t rs = 3 * CC;
    const bf16* Qb  = qkv + (size_t)b * NN * rs + h * DD;
    const bf16* Kb  = Qb + CC;
    const bf16* Vtb = Vt + (size_t)bh * DD * NN;

    bf16x8 qf[2];
    {
        const int qrow = qt * 128 + wave * 16 + l16;
#pragma unroll
        for (int hf = 0; hf < 2; ++hf)
            qf[hf] = *(const bf16x8*)(Qb + (size_t)qrow * rs + hf * 32 + quad * 8);
    }

    f32x4 accO[4];
#pragma unroll
    for (int i = 0; i < 4; ++i) accO[i] = (f32x4){0.f, 0.f, 0.f, 0.f};
    float lsum = 0.f;

    const int srow = lane >> 3;
    const int swz  = (lane & 7) ^ srow;
    const int strow = wave * 8 + srow;

    for (int kt = 0; kt < NN / 64; ++kt) {
        async16(Kb + (size_t)(kt * 64 + strow) * rs + swz * 8,
                &Ks[(wave * 8) * 64]);
        async16(Vtb + (size_t)strow * NN + kt * 64 + swz * 8,
                &Vs[(wave * 8) * 64]);
        __syncthreads();

        // S^T = (Q K^T)^T via swapped operands; scores already exp2-domain
        f32x4 s[4];
#pragma unroll
        for (int nt = 0; nt < 4; ++nt) {
            const int row = nt * 16 + l16;
            bf16x8 kf0 = *(const bf16x8*)(&Ks[row * 64 + (quad ^ r7) * 8]);
            bf16x8 kf1 = *(const bf16x8*)(&Ks[row * 64 + ((quad + 4) ^ r7) * 8]);
            f32x4 z = (f32x4){0.f, 0.f, 0.f, 0.f};
            z = __builtin_amdgcn_mfma_f32_16x16x32_bf16(kf0, qf[0], z, 0, 0, 0);
            s[nt] = __builtin_amdgcn_mfma_f32_16x16x32_bf16(kf1, qf[1], z, 0, 0, 0);
        }

        // p = exp2(s); pack IN-LANE into the two PV A-fragments:
        //   pfa[j] = p[j>>2][j&3]      (keys 0..31 in relabeled order)
        //   pfb[j] = p[2+(j>>2)][j&3]  (keys 32..63)
        bf16x8 pfa, pfb;
#pragma unroll
        for (int nt = 0; nt < 4; ++nt)
#pragma unroll
            for (int r = 0; r < 4; ++r) {
                float pv = __builtin_amdgcn_exp2f(s[nt][r]);
                lsum += pv;
                if (nt < 2) pfa[nt * 4 + r] = (bf16)pv;
                else        pfb[(nt - 2) * 4 + r] = (bf16)pv;
            }

        // PV: V is key-permuted at the source, so fragment chunks are the
        // contiguous b128s at global chunks quad (pfa) and quad+4 (pfb).
#pragma unroll
        for (int nt = 0; nt < 4; ++nt) {
            const int rowd = nt * 16 + l16;
            bf16x8 vf0 = *(const bf16x8*)(&Vs[rowd * 64 + (quad ^ r7) * 8]);
            bf16x8 vf1 = *(const bf16x8*)(&Vs[rowd * 64 + ((quad + 4) ^ r7) * 8]);
            accO[nt] = __builtin_amdgcn_mfma_f32_16x16x32_bf16(pfa, vf0, accO[nt], 0, 0, 0);
            accO[nt] = __builtin_amdgcn_mfma_f32_16x16x32_bf16(pfb, vf1, accO[nt], 0, 0, 0);
        }
        __syncthreads();
    }

    // lsum: reduce over the 4 quads sharing l16 (lane's q = l16)
    lsum += __shfl_xor(lsum, 16, 64);
    lsum += __shfl_xor(lsum, 32, 64);

    // epilogue: accO row q = quad*4+r; fetch 1/lsum from lane quad*4+r
#pragma unroll
    for (int r = 0; r < 4; ++r) {
        float inv = 1.0f / __shfl(lsum, quad * 4 + r, 64);
        int n = qt * 128 + wave * 16 + quad * 4 + r;
#pragma unroll
        for (int nt = 0; nt < 4; ++nt) {
            int col = h * DD + nt * 16 + l16;
            Oqkv[(size_t)(b * NN + n) * rs + 2 * CC + col] = (bf16)(accO[nt][r] * inv);
        }
    }
}

// ---------------------------------------------------------------------------
extern "C" void kernel_launch(void* const* d_in, const int* in_sizes, int n_in,
                              void* d_out, int out_size, void* d_ws, size_t ws_size,
                              hipStream_t stream) {
    const float* x     = (const float*)d_in[0];
    const float* cosb  = (const float*)d_in[1];
    const float* sinb  = (const float*)d_in[2];
    const float* qkv_w = (const float*)d_in[3];
    const float* qnw   = (const float*)d_in[4];
    const float* knw   = (const float*)d_in[5];
    const float* pw    = (const float*)d_in[6];
    const float* pb    = (const float*)d_in[7];
    float* out = (float*)d_out;

    bf16* ws  = (bf16*)d_ws;
    bf16* xb  = ws + OFF_X;
    bf16* qwb = ws + OFF_QW;
    bf16* pwb = ws + OFF_PW;
    bf16* qkv = ws + OFF_QKV;
    bf16* vt  = (bf16*)d_out;   // scratch: Vt [B*H][D][N] = 12.6 MB of the
                                // 25.2 MB out buffer; proj overwrites it last.

    const int M = BB * NN;  // 8192

    // 0) cast MFMA operands to bf16
    convert3<<<1024, 256, 0, stream>>>(x, qkv_w, pw, ws);

    // 1) QKV projection + fused RMSNorm/RoPE/CEXP; v written transposed and
    //    key-permuted to Vt; T1 XCD-chunked block order
    gemm_qkv<<<1152, 256, 0, stream>>>(xb, qwb, qkv, vt, cosb, sinb, qnw, knw);

    // 2) Flash attention (round-11 config) -> v-slice of qkv
    dim3 g4(BB * HH, NN / 128);
    flash_attn<<<g4, 512, 0, stream>>>(qkv, vt, qkv);

    // 3) Output projection (+fp32 bias) -> d_out; T1 XCD-chunked block order
    gemm_proj<<<768, 256, 0, stream>>>(qkv + 2 * CC, pwb, pb, out);
}

// Round 14
// 204.615 us; speedup vs baseline: 1.6590x; 1.0687x over previous
//
#include <hip/hip_runtime.h>
#include <hip/hip_bf16.h>

// Problem constants (B=4, N=2048, C=768, H=12, D=64)
#define BB 4
#define NN 2048
#define CC 768
#define HH 12
#define DD 64

typedef __bf16 bf16;
typedef __attribute__((ext_vector_type(8))) __bf16 bf16x8;
typedef __attribute__((ext_vector_type(4))) __bf16 bf16x4;
typedef __attribute__((ext_vector_type(4))) float f32x4;

// ---- workspace layout (bf16 elems) ----------------------------------------
#define SZ_X    (BB * NN * CC)              // 6291456
#define SZ_QKVW (3 * CC * CC)               // 1769472
#define SZ_PW   (CC * CC)                   // 589824
#define SZ_QKV  ((size_t)BB * NN * 3 * CC)  // 18874368

#define OFF_X    0
#define OFF_QW   (OFF_X + SZ_X)
#define OFF_PW   (OFF_QW + SZ_QKVW)
#define OFF_QKV  (OFF_PW + SZ_PW)           // end = 27525120 elems = 55.1 MB
// Vt [B*H][D][N] (12.6 MB) lives in d_out (25.2 MB f32 scratch until proj).
// Vt's n-dim is PERMUTED within each 64-key group (r11, verified):
//   key = mtg*16 + quad*4 + r  ->  pos = (mtg>>1)*32 + quad*8 + (mtg&1)*4 + r
// so flash's in-lane P fragments contract against contiguous b128 V reads.

// Direct-to-LDS 16B DMA; source chunk XOR-swizzled to kill read conflicts.
__device__ __forceinline__ void async16(const bf16* g, bf16* l) {
    __builtin_amdgcn_global_load_lds(
        (const __attribute__((address_space(1))) unsigned int*)g,
        (__attribute__((address_space(3))) unsigned int*)l, 16, 0, 0);
}

// ---------------------------------------------------------------------------
__device__ __forceinline__ void cast8(const float* __restrict__ src,
                                      bf16* __restrict__ dst, int i) {
    f32x4 a = ((const f32x4*)src)[2 * i];
    f32x4 b = ((const f32x4*)src)[2 * i + 1];
    bf16x8 o;
#pragma unroll
    for (int j = 0; j < 4; ++j) { o[j] = (bf16)a[j]; o[j + 4] = (bf16)b[j]; }
    ((bf16x8*)dst)[i] = o;
}

__global__ __launch_bounds__(256) void convert3(
    const float* __restrict__ x, const float* __restrict__ qkvw,
    const float* __restrict__ pw, bf16* __restrict__ ws) {
    const int t = blockIdx.x * 256 + threadIdx.x;
    const int S = gridDim.x * 256;
    for (int i = t; i < SZ_X / 8;    i += S) cast8(x,    ws + OFF_X,  i);
    for (int i = t; i < SZ_QKVW / 8; i += S) cast8(qkvw, ws + OFF_QW, i);
    for (int i = t; i < SZ_PW / 8;   i += S) cast8(pw,   ws + OFF_PW, i);
}

// ---------------------------------------------------------------------------
// QKV GEMM + fused RMSNorm/RoPE + transposed/key-permuted V store.
// r14: 8 waves x (32-row x 64-col) sub-tiles on the same 128x128 block tile
// (was 4 waves x 64x64).  acc halves to 2x4 f32x4 (32 regs/lane) -> VGPR
// drops ~120->~90, residency ~2x (r13 counters: Occ 17%, Mfma 16%, nothing
// saturated -> latency-bound).  Staging: 4 DMA issues/wave (i*64+wave*8+srow)
// -> identical LDS image/swizzle.  64-wide head stays within one wave, so
// the verified RMS/RoPE epilogue is unchanged (mt<2); V-permute generalizes:
// pos = (btok&32) + quad*8 + mt*4 + r.  T1 XCD-chunked order kept (r13).
// ---------------------------------------------------------------------------
__global__ __launch_bounds__(512) void gemm_qkv(
    const bf16* __restrict__ A, const bf16* __restrict__ W,
    bf16* __restrict__ C, bf16* __restrict__ Vt,
    const float* __restrict__ cosb, const float* __restrict__ sinb,
    const float* __restrict__ qw, const float* __restrict__ kw) {
    __shared__ __align__(16) bf16 As[128 * 64];
    __shared__ __align__(16) bf16 Bs[128 * 64];
    const int tid  = threadIdx.x;
    const int wave = tid >> 6;                 // 0..7
    const int lane = tid & 63;
    const int quad = lane >> 4;
    const int l16  = lane & 15;
    const int id = blockIdx.x;                 // 0..1151
    const int w  = (id & 7) * 144 + (id >> 3); // T1 bijection (1152 = 8*144)
    const int m0 = (w / 18) * 128;
    const int n0 = (w % 18) * 128;
    const int wm = (wave & 3) * 32;            // 32 output rows per wave
    const int wn = (wave >> 2) * 64;           // 64 output cols per wave
    const int srow = lane >> 3;
    const int swz  = (lane & 7) ^ srow;
    const int K = CC;
    const int Nn = 3 * CC;

    f32x4 acc[2][4];
#pragma unroll
    for (int i = 0; i < 2; ++i)
#pragma unroll
        for (int j = 0; j < 4; ++j) acc[i][j] = (f32x4){0.f, 0.f, 0.f, 0.f};

    for (int k0 = 0; k0 < K; k0 += 64) {
#pragma unroll
        for (int i = 0; i < 2; ++i) {
            int row = i * 64 + wave * 8 + srow;
            async16(A + (size_t)(m0 + row) * CC + k0 + swz * 8,
                    &As[(i * 64 + wave * 8) * 64]);
            async16(W + (size_t)(n0 + row) * K + k0 + swz * 8,
                    &Bs[(i * 64 + wave * 8) * 64]);
        }
        __syncthreads();
#pragma unroll
        for (int kk = 0; kk < 2; ++kk) {
            const int slot = ((kk * 4 + quad) ^ (l16 & 7)) * 8;
            bf16x8 af[2], bf[4];
#pragma unroll
            for (int mt = 0; mt < 2; ++mt)
                af[mt] = *(const bf16x8*)(&As[(wm + mt * 16 + l16) * 64 + slot]);
#pragma unroll
            for (int nt = 0; nt < 4; ++nt)
                bf[nt] = *(const bf16x8*)(&Bs[(wn + nt * 16 + l16) * 64 + slot]);
#pragma unroll
            for (int mt = 0; mt < 2; ++mt)
#pragma unroll
                for (int nt = 0; nt < 4; ++nt)
                    acc[mt][nt] = __builtin_amdgcn_mfma_f32_16x16x32_bf16(
                        af[mt], bf[nt], acc[mt][nt], 0, 0, 0);
        }
        __syncthreads();
    }

    const int colblk = n0 + wn;          // 64-aligned; one head of q/k/v
    const int sector = colblk / CC;      // 0=q, 1=k, 2=v
    if (sector == 2) {
        // v: transposed + key-permuted store straight to Vt[bh][d][pos].
        // Wave covers HALF a 64-token group; group-mt = mt + ((btok&32)>>4)
        // collapses to pos = (btok&32) + quad*8 + mt*4 + r.
        const int head = (colblk >> 6) - 24;
        const int btok = m0 + wm;                // multiple of 32
        const int bh   = (btok >> 11) * HH + head;
        const int nl   = btok & (NN - 1);
        const int base = (nl & ~63) + (nl & 32); // group base + half offset
#pragma unroll
        for (int nt = 0; nt < 4; ++nt) {
            const int d = nt * 16 + l16;
            bf16* dst = Vt + ((size_t)bh * DD + d) * NN + base + quad * 8;
#pragma unroll
            for (int mt = 0; mt < 2; ++mt) {
                bf16x4 pk;
#pragma unroll
                for (int r = 0; r < 4; ++r) pk[r] = (bf16)acc[mt][nt][r];
                *(bf16x4*)(dst + mt * 4) = pk;
            }
        }
    } else {
        const float* wp = (sector == 0) ? qw : kw;
        const float qs = (sector == 0) ? 0.18033688f : 1.0f;  // CEXP fold
        float wv[4];
#pragma unroll
        for (int nt = 0; nt < 4; ++nt) wv[nt] = wp[nt * 16 + l16];
#pragma unroll
        for (int mt = 0; mt < 2; ++mt)
#pragma unroll
            for (int r = 0; r < 4; ++r) {
                const int row = m0 + wm + mt * 16 + quad * 4 + r;
                const int n   = row & (NN - 1);
                float v[4];
#pragma unroll
                for (int nt = 0; nt < 4; ++nt) v[nt] = acc[mt][nt][r];
                float ss = v[0] * v[0] + v[1] * v[1] + v[2] * v[2] + v[3] * v[3];
                ss += __shfl_xor(ss, 1, 64);
                ss += __shfl_xor(ss, 2, 64);
                ss += __shfl_xor(ss, 4, 64);
                ss += __shfl_xor(ss, 8, 64);
                const float rn = rsqrtf(ss * (1.0f / 64.0f) + 1e-6f);
#pragma unroll
                for (int nt = 0; nt < 4; ++nt) v[nt] *= rn * wv[nt];
                const float c0 = cosb[n * 32 + l16];
                const float c1 = cosb[n * 32 + 16 + l16];
                const float s0 = sinb[n * 32 + l16];
                const float s1 = sinb[n * 32 + 16 + l16];
                float y[4];
                y[0] = v[0] * c0 - v[2] * s0;
                y[1] = v[1] * c1 - v[3] * s1;
                y[2] = v[2] * c0 + v[0] * s0;
                y[3] = v[3] * c1 + v[1] * s1;
#pragma unroll
                for (int nt = 0; nt < 4; ++nt) {
                    int col = colblk + nt * 16 + l16;
                    C[(size_t)row * Nn + col] = (bf16)(y[nt] * qs);
                }
            }
    }
}

// ---------------------------------------------------------------------------
// Output projection GEMM, 128x64 tiles + T1 XCD-chunked order (r13,
// unchanged).
// ---------------------------------------------------------------------------
__global__ __launch_bounds__(256) void gemm_proj(
    const bf16* __restrict__ A, const bf16* __restrict__ W,
    const float* __restrict__ bias, float* __restrict__ C) {
    __shared__ __align__(16) bf16 As[128 * 64];
    __shared__ __align__(16) bf16 Bs[64 * 64];
    const int tid  = threadIdx.x;
    const int wave = tid >> 6;
    const int lane = tid & 63;
    const int quad = lane >> 4;
    const int l16  = lane & 15;
    const int id = blockIdx.x;                // 0..767
    const int w  = (id & 7) * 96 + (id >> 3); // bijective (768 = 8*96)
    const int m0 = (w / 12) * 128;
    const int n0 = (w % 12) * 64;
    const int wm = (wave >> 1) * 64;
    const int wn = (wave & 1) * 32;
    const int srow = lane >> 3;
    const int swz  = (lane & 7) ^ srow;
    const int lda = 3 * CC;
    const int K = CC;

    f32x4 acc[4][2];
#pragma unroll
    for (int i = 0; i < 4; ++i)
#pragma unroll
        for (int j = 0; j < 2; ++j) acc[i][j] = (f32x4){0.f, 0.f, 0.f, 0.f};

    for (int k0 = 0; k0 < K; k0 += 64) {
#pragma unroll
        for (int i = 0; i < 4; ++i) {
            int row = i * 32 + wave * 8 + srow;
            async16(A + (size_t)(m0 + row) * lda + k0 + swz * 8,
                    &As[(i * 32 + wave * 8) * 64]);
        }
#pragma unroll
        for (int i = 0; i < 2; ++i) {
            int row = i * 32 + wave * 8 + srow;
            async16(W + (size_t)(n0 + row) * K + k0 + swz * 8,
                    &Bs[(i * 32 + wave * 8) * 64]);
        }
        __syncthreads();
#pragma unroll
        for (int kk = 0; kk < 2; ++kk) {
            const int slot = ((kk * 4 + quad) ^ (l16 & 7)) * 8;
            bf16x8 af[4], bf[2];
#pragma unroll
            for (int mt = 0; mt < 4; ++mt)
                af[mt] = *(const bf16x8*)(&As[(wm + mt * 16 + l16) * 64 + slot]);
#pragma unroll
            for (int nt = 0; nt < 2; ++nt)
                bf[nt] = *(const bf16x8*)(&Bs[(wn + nt * 16 + l16) * 64 + slot]);
#pragma unroll
            for (int mt = 0; mt < 4; ++mt)
#pragma unroll
                for (int nt = 0; nt < 2; ++nt)
                    acc[mt][nt] = __builtin_amdgcn_mfma_f32_16x16x32_bf16(
                        af[mt], bf[nt], acc[mt][nt], 0, 0, 0);
        }
        __syncthreads();
    }
#pragma unroll
    for (int mt = 0; mt < 4; ++mt)
#pragma unroll
        for (int nt = 0; nt < 2; ++nt)
#pragma unroll
            for (int r = 0; r < 4; ++r) {
                int row = m0 + wm + mt * 16 + quad * 4 + r;
                int col = n0 + wn + nt * 16 + l16;
                C[(size_t)row * CC + col] = acc[mt][nt][r] + bias[col];
            }
}

// ---------------------------------------------------------------------------
// Flash attention — round-11 version VERBATIM (best measured: 61.8us =
// ds_read_b128 roofline, bank conflicts 0, Occ 46%).
// ---------------------------------------------------------------------------
__global__ __launch_bounds__(512) void flash_attn(
    const bf16* __restrict__ qkv, const bf16* __restrict__ Vt,
    bf16* __restrict__ Oqkv) {
    __shared__ __align__(16) bf16 Ks[64 * 64];       // [key][d] swizzled
    __shared__ __align__(16) bf16 Vs[64 * 64];       // [d][pos] swizzled
    const int tid  = threadIdx.x;
    const int wave = tid >> 6;
    const int lane = tid & 63;
    const int quad = lane >> 4;
    const int l16  = lane & 15;
    const int r7   = l16 & 7;
    const int bh = blockIdx.x;
    const int qt = blockIdx.y;
    const int b = bh / HH, h = bh % HH;
    const size_t rs = 3 * CC;
    const bf16* Qb  = qkv + (size_t)b * NN * rs + h * DD;
    const bf16* Kb  = Qb + CC;
    const bf16* Vtb = Vt + (size_t)bh * DD * NN;

    bf16x8 qf[2];
    {
        const int qrow = qt * 128 + wave * 16 + l16;
#pragma unroll
        for (int hf = 0; hf < 2; ++hf)
            qf[hf] = *(const bf16x8*)(Qb + (size_t)qrow * rs + hf * 32 + quad * 8);
    }

    f32x4 accO[4];
#pragma unroll
    for (int i = 0; i < 4; ++i) accO[i] = (f32x4){0.f, 0.f, 0.f, 0.f};
    float lsum = 0.f;

    const int srow = lane >> 3;
    const int swz  = (lane & 7) ^ srow;
    const int strow = wave * 8 + srow;

    for (int kt = 0; kt < NN / 64; ++kt) {
        async16(Kb + (size_t)(kt * 64 + strow) * rs + swz * 8,
                &Ks[(wave * 8) * 64]);
        async16(Vtb + (size_t)strow * NN + kt * 64 + swz * 8,
                &Vs[(wave * 8) * 64]);
        __syncthreads();

        // S^T = (Q K^T)^T via swapped operands; scores already exp2-domain
        f32x4 s[4];
#pragma unroll
        for (int nt = 0; nt < 4; ++nt) {
            const int row = nt * 16 + l16;
            bf16x8 kf0 = *(const bf16x8*)(&Ks[row * 64 + (quad ^ r7) * 8]);
            bf16x8 kf1 = *(const bf16x8*)(&Ks[row * 64 + ((quad + 4) ^ r7) * 8]);
            f32x4 z = (f32x4){0.f, 0.f, 0.f, 0.f};
            z = __builtin_amdgcn_mfma_f32_16x16x32_bf16(kf0, qf[0], z, 0, 0, 0);
            s[nt] = __builtin_amdgcn_mfma_f32_16x16x32_bf16(kf1, qf[1], z, 0, 0, 0);
        }

        // p = exp2(s); pack IN-LANE into the two PV A-fragments
        bf16x8 pfa, pfb;
#pragma unroll
        for (int nt = 0; nt < 4; ++nt)
#pragma unroll
            for (int r = 0; r < 4; ++r) {
                float pv = __builtin_amdgcn_exp2f(s[nt][r]);
                lsum += pv;
                if (nt < 2) pfa[nt * 4 + r] = (bf16)pv;
                else        pfb[(nt - 2) * 4 + r] = (bf16)pv;
            }

        // PV: V is key-permuted at the source -> contiguous b128 fragments
#pragma unroll
        for (int nt = 0; nt < 4; ++nt) {
            const int rowd = nt * 16 + l16;
            bf16x8 vf0 = *(const bf16x8*)(&Vs[rowd * 64 + (quad ^ r7) * 8]);
            bf16x8 vf1 = *(const bf16x8*)(&Vs[rowd * 64 + ((quad + 4) ^ r7) * 8]);
            accO[nt] = __builtin_amdgcn_mfma_f32_16x16x32_bf16(pfa, vf0, accO[nt], 0, 0, 0);
            accO[nt] = __builtin_amdgcn_mfma_f32_16x16x32_bf16(pfb, vf1, accO[nt], 0, 0, 0);
        }
        __syncthreads();
    }

    // lsum: reduce over the 4 quads sharing l16 (lane's q = l16)
    lsum += __shfl_xor(lsum, 16, 64);
    lsum += __shfl_xor(lsum, 32, 64);

    // epilogue: accO row q = quad*4+r; fetch 1/lsum from lane quad*4+r
#pragma unroll
    for (int r = 0; r < 4; ++r) {
        float inv = 1.0f / __shfl(lsum, quad * 4 + r, 64);
        int n = qt * 128 + wave * 16 + quad * 4 + r;
#pragma unroll
        for (int nt = 0; nt < 4; ++nt) {
            int col = h * DD + nt * 16 + l16;
            Oqkv[(size_t)(b * NN + n) * rs + 2 * CC + col] = (bf16)(accO[nt][r] * inv);
        }
    }
}

// ---------------------------------------------------------------------------
extern "C" void kernel_launch(void* const* d_in, const int* in_sizes, int n_in,
                              void* d_out, int out_size, void* d_ws, size_t ws_size,
                              hipStream_t stream) {
    const float* x     = (const float*)d_in[0];
    const float* cosb  = (const float*)d_in[1];
    const float* sinb  = (const float*)d_in[2];
    const float* qkv_w = (const float*)d_in[3];
    const float* qnw   = (const float*)d_in[4];
    const float* knw   = (const float*)d_in[5];
    const float* pw    = (const float*)d_in[6];
    const float* pb    = (const float*)d_in[7];
    float* out = (float*)d_out;

    bf16* ws  = (bf16*)d_ws;
    bf16* xb  = ws + OFF_X;
    bf16* qwb = ws + OFF_QW;
    bf16* pwb = ws + OFF_PW;
    bf16* qkv = ws + OFF_QKV;
    bf16* vt  = (bf16*)d_out;   // scratch: Vt [B*H][D][N] = 12.6 MB of the
                                // 25.2 MB out buffer; proj overwrites it last.

    const int M = BB * NN;  // 8192

    // 0) cast MFMA operands to bf16
    convert3<<<1024, 256, 0, stream>>>(x, qkv_w, pw, ws);

    // 1) QKV projection + fused RMSNorm/RoPE/CEXP; 8-wave blocks (r14)
    gemm_qkv<<<1152, 512, 0, stream>>>(xb, qwb, qkv, vt, cosb, sinb, qnw, knw);

    // 2) Flash attention (round-11 config) -> v-slice of qkv
    dim3 g4(BB * HH, NN / 128);
    flash_attn<<<g4, 512, 0, stream>>>(qkv, vt, qkv);

    // 3) Output projection (+fp32 bias) -> d_out; T1 XCD-chunked block order
    gemm_proj<<<768, 256, 0, stream>>>(qkv + 2 * CC, pwb, pb, out);
}